// Round 1
// baseline (566.919 us; speedup 1.0000x reference)
//
#include <hip/hip_runtime.h>
#include <hip/hip_bf16.h>
#include <cstdint>
#include <cstddef>

// Problem constants
#define SEQ    4096
#define NB     4
#define DIM    1024
#define NHEAD  16
#define HDIM   64
#define MROWS  (NB * SEQ)   // 16384
#define SCALEF 0.125f       // 64^-0.5

typedef short          s16x8 __attribute__((ext_vector_type(8)));
typedef unsigned short u16x8 __attribute__((ext_vector_type(8)));
typedef float          f32x4 __attribute__((ext_vector_type(4)));
typedef unsigned short u16;

__device__ __forceinline__ u16 f2bf(float f) {
  uint32_t u = __builtin_bit_cast(uint32_t, f);
  return (u16)((u + 0x7fffu + ((u >> 16) & 1u)) >> 16);   // RNE
}
__device__ __forceinline__ float bf2f(u16 u) {
  return __builtin_bit_cast(float, (uint32_t)u << 16);
}
__device__ __forceinline__ void gload_lds16(const void* g, void* l) {
  __builtin_amdgcn_global_load_lds(
      (const __attribute__((address_space(1))) void*)g,
      (__attribute__((address_space(3))) void*)l, 16, 0, 0);
}

// ---------------------------------------------------------------------------
// Convert the four [DIM,DIM] fp32 weight matrices to bf16.
// ---------------------------------------------------------------------------
__global__ __launch_bounds__(256) void cvt_weights(
    const float* __restrict__ w0, const float* __restrict__ w1,
    const float* __restrict__ w2, const float* __restrict__ w3,
    u16* __restrict__ o0, u16* __restrict__ o1,
    u16* __restrict__ o2, u16* __restrict__ o3)
{
  int t = blockIdx.x * 256 + threadIdx.x;        // 0 .. 524287
  int m = t >> 17;                               // which matrix (131072 thr each)
  int off = (t & 131071) * 8;                    // 8 floats per thread
  const float* s = (m == 0) ? w0 : (m == 1) ? w1 : (m == 2) ? w2 : w3;
  u16*         d = (m == 0) ? o0 : (m == 1) ? o1 : (m == 2) ? o2 : o3;
  float4 a = ((const float4*)(s + off))[0];
  float4 b = ((const float4*)(s + off))[1];
  u16x8 p;
  p[0] = f2bf(a.x); p[1] = f2bf(a.y); p[2] = f2bf(a.z); p[3] = f2bf(a.w);
  p[4] = f2bf(b.x); p[5] = f2bf(b.y); p[6] = f2bf(b.z); p[7] = f2bf(b.w);
  *(u16x8*)(d + off) = p;
}

// ---------------------------------------------------------------------------
// QKV projection GEMM: C = A(fp32) @ W^T + bias, C stored bf16.
// 128x128 tile, BK=32, 4 waves (2x2 of 64x64), mfma_f32_16x16x32_bf16.
// A: fp32 reg-staged + cvt to LDS.  W(bf16, row=outcol, k-contig): global_load_lds.
// blockIdx.z selects q/k/v.
// ---------------------------------------------------------------------------
__global__ __launch_bounds__(256) void gemm_qkv(
    const float* __restrict__ qin, const float* __restrict__ kin, const float* __restrict__ vin,
    const u16* __restrict__ Wq, const u16* __restrict__ Wk, const u16* __restrict__ Wv,
    const float* __restrict__ bq, const float* __restrict__ bk, const float* __restrict__ bv,
    u16* __restrict__ Qo, u16* __restrict__ Ko, u16* __restrict__ Vo)
{
  __shared__ __align__(16) u16 As[128 * 32];   // [row][k] k-contig, 8KB
  __shared__ __align__(16) u16 Bs[128 * 32];   // [outcol][k] k-contig, 8KB

  const int z = blockIdx.z;
  const float* A    = (z == 0) ? qin : (z == 1) ? kin : vin;
  const u16*   W    = (z == 0) ? Wq  : (z == 1) ? Wk  : Wv;
  const float* bias = (z == 0) ? bq  : (z == 1) ? bk  : bv;
  u16*         C    = (z == 0) ? Qo  : (z == 1) ? Ko  : Vo;

  const int tid = threadIdx.x;
  const int lane = tid & 63, wave = tid >> 6;
  const int wr = wave >> 1, wc = wave & 1;
  const int fr = lane & 15, fq = lane >> 4;
  const int m0 = blockIdx.x * 128, n0 = blockIdx.y * 128;

  const int sr = tid >> 1, sh = tid & 1;   // A staging: row, half(16 floats)
  const float* ag = A + (size_t)(m0 + sr) * DIM + sh * 16;

  f32x4 acc[4][4];
  #pragma unroll
  for (int i = 0; i < 4; ++i)
    #pragma unroll
    for (int j = 0; j < 4; ++j) acc[i][j] = (f32x4){0.f, 0.f, 0.f, 0.f};

  for (int kt = 0; kt < DIM / 32; ++kt) {
    // ---- stage W tile via global_load_lds (2 x 16B per thread) ----
    #pragma unroll
    for (int i = 0; i < 2; ++i) {
      int ci = i * 256 + wave * 64 + lane;                   // 16B chunk id
      const u16* g = W + (size_t)(n0 + (ci >> 2)) * DIM + kt * 32 + (ci & 3) * 8;
      gload_lds16(g, (char*)Bs + (i * 256 + wave * 64) * 16);
    }
    // ---- stage A tile: 16 fp32 -> 16 bf16 per thread ----
    {
      const float* ga = ag + kt * 32;
      float4 v0 = ((const float4*)ga)[0];
      float4 v1 = ((const float4*)ga)[1];
      float4 v2 = ((const float4*)ga)[2];
      float4 v3 = ((const float4*)ga)[3];
      u16x8 p0, p1;
      p0[0] = f2bf(v0.x); p0[1] = f2bf(v0.y); p0[2] = f2bf(v0.z); p0[3] = f2bf(v0.w);
      p0[4] = f2bf(v1.x); p0[5] = f2bf(v1.y); p0[6] = f2bf(v1.z); p0[7] = f2bf(v1.w);
      p1[0] = f2bf(v2.x); p1[1] = f2bf(v2.y); p1[2] = f2bf(v2.z); p1[3] = f2bf(v2.w);
      p1[4] = f2bf(v3.x); p1[5] = f2bf(v3.y); p1[6] = f2bf(v3.z); p1[7] = f2bf(v3.w);
      *(u16x8*)((char*)As + sr * 64 + sh * 32)      = p0;
      *(u16x8*)((char*)As + sr * 64 + sh * 32 + 16) = p1;
    }
    __syncthreads();
    // ---- fragments + MFMA ----
    s16x8 a[4], b[4];
    #pragma unroll
    for (int mi = 0; mi < 4; ++mi)
      a[mi] = *(const s16x8*)((const char*)As + (wr * 64 + mi * 16 + fr) * 64 + fq * 16);
    #pragma unroll
    for (int ni = 0; ni < 4; ++ni)
      b[ni] = *(const s16x8*)((const char*)Bs + (wc * 64 + ni * 16 + fr) * 64 + fq * 16);
    #pragma unroll
    for (int mi = 0; mi < 4; ++mi)
      #pragma unroll
      for (int ni = 0; ni < 4; ++ni)
        acc[mi][ni] = __builtin_amdgcn_mfma_f32_16x16x32_bf16(a[mi], b[ni], acc[mi][ni], 0, 0, 0);
    __syncthreads();
  }

  // ---- epilogue: +bias, store bf16 ----
  #pragma unroll
  for (int ni = 0; ni < 4; ++ni) {
    int col = n0 + wc * 64 + ni * 16 + fr;
    float bvv = bias[col];
    #pragma unroll
    for (int mi = 0; mi < 4; ++mi) {
      #pragma unroll
      for (int r = 0; r < 4; ++r) {
        int row = m0 + wr * 64 + mi * 16 + fq * 4 + r;
        C[(size_t)row * DIM + col] = f2bf(acc[mi][ni][r] + bvv);
      }
    }
  }
}

// ---------------------------------------------------------------------------
// Output GEMM: out = Qb(bf16) @ Wo^T + c2[b]  (fp32 out). Both operands via
// global_load_lds.
// ---------------------------------------------------------------------------
__global__ __launch_bounds__(256) void gemm_out(
    const u16* __restrict__ Qb, const u16* __restrict__ Wo_bf,
    const float* __restrict__ c2, float* __restrict__ out)
{
  __shared__ __align__(16) u16 As[128 * 32];
  __shared__ __align__(16) u16 Bs[128 * 32];

  const int tid = threadIdx.x;
  const int lane = tid & 63, wave = tid >> 6;
  const int wr = wave >> 1, wc = wave & 1;
  const int fr = lane & 15, fq = lane >> 4;
  const int m0 = blockIdx.x * 128, n0 = blockIdx.y * 128;
  const int bidx = m0 >> 12;   // batch (4096 rows per b, tiles never straddle)

  f32x4 acc[4][4];
  #pragma unroll
  for (int i = 0; i < 4; ++i)
    #pragma unroll
    for (int j = 0; j < 4; ++j) acc[i][j] = (f32x4){0.f, 0.f, 0.f, 0.f};

  for (int kt = 0; kt < DIM / 32; ++kt) {
    #pragma unroll
    for (int i = 0; i < 2; ++i) {
      int ci = i * 256 + wave * 64 + lane;
      const u16* ga = Qb + (size_t)(m0 + (ci >> 2)) * DIM + kt * 32 + (ci & 3) * 8;
      gload_lds16(ga, (char*)As + (i * 256 + wave * 64) * 16);
      const u16* gb = Wo_bf + (size_t)(n0 + (ci >> 2)) * DIM + kt * 32 + (ci & 3) * 8;
      gload_lds16(gb, (char*)Bs + (i * 256 + wave * 64) * 16);
    }
    __syncthreads();
    s16x8 a[4], b[4];
    #pragma unroll
    for (int mi = 0; mi < 4; ++mi)
      a[mi] = *(const s16x8*)((const char*)As + (wr * 64 + mi * 16 + fr) * 64 + fq * 16);
    #pragma unroll
    for (int ni = 0; ni < 4; ++ni)
      b[ni] = *(const s16x8*)((const char*)Bs + (wc * 64 + ni * 16 + fr) * 64 + fq * 16);
    #pragma unroll
    for (int mi = 0; mi < 4; ++mi)
      #pragma unroll
      for (int ni = 0; ni < 4; ++ni)
        acc[mi][ni] = __builtin_amdgcn_mfma_f32_16x16x32_bf16(a[mi], b[ni], acc[mi][ni], 0, 0, 0);
    __syncthreads();
  }

  #pragma unroll
  for (int ni = 0; ni < 4; ++ni) {
    int col = n0 + wc * 64 + ni * 16 + fr;
    float cv = c2[bidx * DIM + col];
    #pragma unroll
    for (int mi = 0; mi < 4; ++mi) {
      #pragma unroll
      for (int r = 0; r < 4; ++r) {
        int row = m0 + wr * 64 + mi * 16 + fq * 4 + r;
        out[(size_t)row * DIM + col] = acc[mi][ni][r] + cv;
      }
    }
  }
}

// ---------------------------------------------------------------------------
// Per-(b,h) fused reduction: alpha softmax -> global_q -> beta softmax ->
// global_v.  64 blocks x 256 threads.
// ---------------------------------------------------------------------------
__global__ __launch_bounds__(256) void reduce_global(
    const u16* __restrict__ Qb, const u16* __restrict__ Kb, const u16* __restrict__ Vb,
    const float* __restrict__ qalpha, const float* __restrict__ kbeta,
    float* __restrict__ gvout)
{
  __shared__ float wl[SEQ];        // 16KB logits/weights
  __shared__ float vec[HDIM];
  __shared__ float red[4];
  __shared__ float part[256];
  __shared__ float gqs[HDIM];

  const int bh = blockIdx.x, b = bh >> 4, h = bh & 15;
  const int tid = threadIdx.x, lane = tid & 63, wave = tid >> 6;
  const size_t base = (size_t)b * SEQ * DIM + (size_t)h * HDIM;
  const int rsub = lane >> 3, ch = lane & 7;

  // ================= alpha pass (Q) =================
  if (tid < HDIM) vec[tid] = qalpha[h * HDIM + tid];
  __syncthreads();

  #pragma unroll 2
  for (int i0 = 0; i0 < SEQ; i0 += 32) {
    int row = i0 + wave * 8 + rsub;
    u16x8 u = *(const u16x8*)(Qb + base + (size_t)row * DIM + ch * 8);
    float dot = 0.f;
    #pragma unroll
    for (int j = 0; j < 8; ++j) dot += bf2f(u[j]) * vec[ch * 8 + j];
    dot += __shfl_xor(dot, 1);
    dot += __shfl_xor(dot, 2);
    dot += __shfl_xor(dot, 4);
    if (ch == 0) wl[row] = dot * SCALEF;
  }
  __syncthreads();

  float m = -1e30f;
  for (int i = tid; i < SEQ; i += 256) m = fmaxf(m, wl[i]);
  #pragma unroll
  for (int o = 32; o; o >>= 1) m = fmaxf(m, __shfl_down(m, o));
  if (lane == 0) red[wave] = m;
  __syncthreads();
  m = fmaxf(fmaxf(red[0], red[1]), fmaxf(red[2], red[3]));
  __syncthreads();

  float s = 0.f;
  for (int i = tid; i < SEQ; i += 256) { float e = __expf(wl[i] - m); wl[i] = e; s += e; }
  #pragma unroll
  for (int o = 32; o; o >>= 1) s += __shfl_down(s, o);
  if (lane == 0) red[wave] = s;
  __syncthreads();
  s = red[0] + red[1] + red[2] + red[3];

  {
    const int d = tid & 63, g = tid >> 6;
    float acc = 0.f;
    const u16* qd = Qb + base + d;
    #pragma unroll 8
    for (int i = g; i < SEQ; i += 4) acc += wl[i] * bf2f(qd[(size_t)i * DIM]);
    part[tid] = acc;
  }
  __syncthreads();
  if (tid < HDIM) gqs[tid] = (part[tid] + part[tid + 64] + part[tid + 128] + part[tid + 192]) / s;
  __syncthreads();

  // ================= beta pass (K -> weights, V -> global_v) =================
  if (tid < HDIM) vec[tid] = gqs[tid] * kbeta[h * HDIM + tid];
  __syncthreads();

  #pragma unroll 2
  for (int i0 = 0; i0 < SEQ; i0 += 32) {
    int row = i0 + wave * 8 + rsub;
    u16x8 u = *(const u16x8*)(Kb + base + (size_t)row * DIM + ch * 8);
    float dot = 0.f;
    #pragma unroll
    for (int j = 0; j < 8; ++j) dot += bf2f(u[j]) * vec[ch * 8 + j];
    dot += __shfl_xor(dot, 1);
    dot += __shfl_xor(dot, 2);
    dot += __shfl_xor(dot, 4);
    if (ch == 0) wl[row] = dot * SCALEF;
  }
  __syncthreads();

  float m2 = -1e30f;
  for (int i = tid; i < SEQ; i += 256) m2 = fmaxf(m2, wl[i]);
  #pragma unroll
  for (int o = 32; o; o >>= 1) m2 = fmaxf(m2, __shfl_down(m2, o));
  if (lane == 0) red[wave] = m2;
  __syncthreads();
  m2 = fmaxf(fmaxf(red[0], red[1]), fmaxf(red[2], red[3]));
  __syncthreads();

  float s2 = 0.f;
  for (int i = tid; i < SEQ; i += 256) { float e = __expf(wl[i] - m2); wl[i] = e; s2 += e; }
  #pragma unroll
  for (int o = 32; o; o >>= 1) s2 += __shfl_down(s2, o);
  if (lane == 0) red[wave] = s2;
  __syncthreads();
  s2 = red[0] + red[1] + red[2] + red[3];

  {
    const int d = tid & 63, g = tid >> 6;
    float acc = 0.f;
    const u16* vd = Vb + base + d;
    #pragma unroll 8
    for (int i = g; i < SEQ; i += 4) acc += wl[i] * bf2f(vd[(size_t)i * DIM]);
    part[tid] = acc;
  }
  __syncthreads();
  if (tid < HDIM)
    gvout[bh * HDIM + tid] = (part[tid] + part[tid + 64] + part[tid + 128] + part[tid + 192]) / s2;
}

// ---------------------------------------------------------------------------
// c2[b,j] = sum_k gv[b,k]*Wo[j,k] + bo[j].  One wave per (b,j); 1024 blocks.
// ---------------------------------------------------------------------------
__global__ __launch_bounds__(256) void gv_wo_kernel(
    const float* __restrict__ gv, const float* __restrict__ Wo,
    const float* __restrict__ bo, float* __restrict__ c2)
{
  int wid = blockIdx.x * 4 + (threadIdx.x >> 6);  // 0..4095 = b*1024 + j
  int b = wid >> 10, j = wid & 1023;
  int lane = threadIdx.x & 63;
  float acc = 0.f;
  #pragma unroll
  for (int c = 0; c < 16; ++c) {
    int kk = c * 64 + lane;
    acc += gv[b * DIM + kk] * Wo[(size_t)j * DIM + kk];
  }
  #pragma unroll
  for (int o = 32; o; o >>= 1) acc += __shfl_down(acc, o);
  if (lane == 0) c2[wid] = acc + bo[j];
}

// ---------------------------------------------------------------------------
extern "C" void kernel_launch(void* const* d_in, const int* in_sizes, int n_in,
                              void* d_out, int out_size, void* d_ws, size_t ws_size,
                              hipStream_t stream) {
  const float* q  = (const float*)d_in[0];
  const float* k  = (const float*)d_in[1];
  const float* v  = (const float*)d_in[2];
  const float* Wq = (const float*)d_in[3];
  const float* bq = (const float*)d_in[4];
  const float* Wk = (const float*)d_in[5];
  const float* bk = (const float*)d_in[6];
  const float* Wv = (const float*)d_in[7];
  const float* bv = (const float*)d_in[8];
  const float* qa = (const float*)d_in[9];
  const float* kb = (const float*)d_in[10];
  const float* Wo = (const float*)d_in[11];
  const float* bo = (const float*)d_in[12];
  float* out = (float*)d_out;

  // workspace layout (~109 MB)
  u16* Qb  = (u16*)d_ws;
  u16* Kb  = Qb + (size_t)MROWS * DIM;
  u16* Vb  = Kb + (size_t)MROWS * DIM;
  u16* Wqb = Vb + (size_t)MROWS * DIM;
  u16* Wkb = Wqb + (size_t)DIM * DIM;
  u16* Wvb = Wkb + (size_t)DIM * DIM;
  u16* Wob = Wvb + (size_t)DIM * DIM;
  float* gv = (float*)(Wob + (size_t)DIM * DIM);
  float* c2 = gv + NB * DIM;

  cvt_weights<<<2048, 256, 0, stream>>>(Wq, Wk, Wv, Wo, Wqb, Wkb, Wvb, Wob);
  gemm_qkv<<<dim3(128, 8, 3), 256, 0, stream>>>(q, k, v, Wqb, Wkb, Wvb,
                                                bq, bk, bv, Qb, Kb, Vb);
  reduce_global<<<64, 256, 0, stream>>>(Qb, Kb, Vb, qa, kb, gv);
  gv_wo_kernel<<<1024, 256, 0, stream>>>(gv, Wo, bo, c2);
  gemm_out<<<dim3(128, 8, 1), 256, 0, stream>>>(Qb, Wob, c2, out);
}

// Round 2
// 365.803 us; speedup vs baseline: 1.5498x; 1.5498x over previous
//
#include <hip/hip_runtime.h>
#include <hip/hip_bf16.h>
#include <cstdint>
#include <cstddef>

// Problem constants
#define SEQ    4096
#define NB     4
#define DIM    1024
#define NHEAD  16
#define HDIM   64
#define MROWS  (NB * SEQ)   // 16384
#define SCALEF 0.125f       // 64^-0.5

typedef short          s16x8 __attribute__((ext_vector_type(8)));
typedef unsigned short u16x8 __attribute__((ext_vector_type(8)));
typedef float          f32x4 __attribute__((ext_vector_type(4)));
typedef unsigned short u16;

__device__ __forceinline__ u16 f2bf(float f) {
  uint32_t u = __builtin_bit_cast(uint32_t, f);
  return (u16)((u + 0x7fffu + ((u >> 16) & 1u)) >> 16);   // RNE
}
__device__ __forceinline__ float bf2f(u16 u) {
  return __builtin_bit_cast(float, (uint32_t)u << 16);
}
__device__ __forceinline__ void gload_lds16(const void* g, void* l) {
  __builtin_amdgcn_global_load_lds(
      (const __attribute__((address_space(1))) void*)g,
      (__attribute__((address_space(3))) void*)l, 16, 0, 0);
}

// ---------------------------------------------------------------------------
// Convert the four [DIM,DIM] fp32 weight matrices to bf16.
// ---------------------------------------------------------------------------
__global__ __launch_bounds__(256) void cvt_weights(
    const float* __restrict__ w0, const float* __restrict__ w1,
    const float* __restrict__ w2, const float* __restrict__ w3,
    u16* __restrict__ o0, u16* __restrict__ o1,
    u16* __restrict__ o2, u16* __restrict__ o3)
{
  int t = blockIdx.x * 256 + threadIdx.x;        // 0 .. 524287
  int m = t >> 17;                               // which matrix
  int off = (t & 131071) * 8;                    // 8 floats per thread
  const float* s = (m == 0) ? w0 : (m == 1) ? w1 : (m == 2) ? w2 : w3;
  u16*         d = (m == 0) ? o0 : (m == 1) ? o1 : (m == 2) ? o2 : o3;
  float4 a = ((const float4*)(s + off))[0];
  float4 b = ((const float4*)(s + off))[1];
  u16x8 p;
  p[0] = f2bf(a.x); p[1] = f2bf(a.y); p[2] = f2bf(a.z); p[3] = f2bf(a.w);
  p[4] = f2bf(b.x); p[5] = f2bf(b.y); p[6] = f2bf(b.z); p[7] = f2bf(b.w);
  *(u16x8*)(d + off) = p;
}

// ---------------------------------------------------------------------------
// QKV projection GEMM: C = A(fp32) @ W^T + bias, C stored bf16.
// 128x128 tile, BK=32, 4 waves (2x2 of 64x64), mfma_f32_16x16x32_bf16.
// z==0 additionally emits alpha logits la[b*16+h][n] (fused: the wave's
// fr-group holds the full 64-d head slice of each Q row).
// ---------------------------------------------------------------------------
__global__ __launch_bounds__(256) void gemm_qkv(
    const float* __restrict__ qin, const float* __restrict__ kin, const float* __restrict__ vin,
    const u16* __restrict__ Wq, const u16* __restrict__ Wk, const u16* __restrict__ Wv,
    const float* __restrict__ bq, const float* __restrict__ bk, const float* __restrict__ bv,
    u16* __restrict__ Qo, u16* __restrict__ Ko, u16* __restrict__ Vo,
    const float* __restrict__ qalpha, float* __restrict__ la)
{
  __shared__ __align__(16) u16 As[128 * 32];   // [row][k] k-contig, 8KB
  __shared__ __align__(16) u16 Bs[128 * 32];   // [outcol][k] k-contig, 8KB

  const int z = blockIdx.z;
  const float* A    = (z == 0) ? qin : (z == 1) ? kin : vin;
  const u16*   W    = (z == 0) ? Wq  : (z == 1) ? Wk  : Wv;
  const float* bias = (z == 0) ? bq  : (z == 1) ? bk  : bv;
  u16*         C    = (z == 0) ? Qo  : (z == 1) ? Ko  : Vo;

  const int tid = threadIdx.x;
  const int lane = tid & 63, wave = tid >> 6;
  const int wr = wave >> 1, wc = wave & 1;
  const int fr = lane & 15, fq = lane >> 4;
  const int m0 = blockIdx.x * 128, n0 = blockIdx.y * 128;

  const int sr = tid >> 1, sh = tid & 1;   // A staging: row, half(16 floats)
  const float* ag = A + (size_t)(m0 + sr) * DIM + sh * 16;

  f32x4 acc[4][4];
  #pragma unroll
  for (int i = 0; i < 4; ++i)
    #pragma unroll
    for (int j = 0; j < 4; ++j) acc[i][j] = (f32x4){0.f, 0.f, 0.f, 0.f};

  for (int kt = 0; kt < DIM / 32; ++kt) {
    #pragma unroll
    for (int i = 0; i < 2; ++i) {
      int ci = i * 256 + wave * 64 + lane;                   // 16B chunk id
      const u16* g = W + (size_t)(n0 + (ci >> 2)) * DIM + kt * 32 + (ci & 3) * 8;
      gload_lds16(g, (char*)Bs + (i * 256 + wave * 64) * 16);
    }
    {
      const float* ga = ag + kt * 32;
      float4 v0 = ((const float4*)ga)[0];
      float4 v1 = ((const float4*)ga)[1];
      float4 v2 = ((const float4*)ga)[2];
      float4 v3 = ((const float4*)ga)[3];
      u16x8 p0, p1;
      p0[0] = f2bf(v0.x); p0[1] = f2bf(v0.y); p0[2] = f2bf(v0.z); p0[3] = f2bf(v0.w);
      p0[4] = f2bf(v1.x); p0[5] = f2bf(v1.y); p0[6] = f2bf(v1.z); p0[7] = f2bf(v1.w);
      p1[0] = f2bf(v2.x); p1[1] = f2bf(v2.y); p1[2] = f2bf(v2.z); p1[3] = f2bf(v2.w);
      p1[4] = f2bf(v3.x); p1[5] = f2bf(v3.y); p1[6] = f2bf(v3.z); p1[7] = f2bf(v3.w);
      *(u16x8*)((char*)As + sr * 64 + sh * 32)      = p0;
      *(u16x8*)((char*)As + sr * 64 + sh * 32 + 16) = p1;
    }
    __syncthreads();
    s16x8 a[4], b[4];
    #pragma unroll
    for (int mi = 0; mi < 4; ++mi)
      a[mi] = *(const s16x8*)((const char*)As + (wr * 64 + mi * 16 + fr) * 64 + fq * 16);
    #pragma unroll
    for (int ni = 0; ni < 4; ++ni)
      b[ni] = *(const s16x8*)((const char*)Bs + (wc * 64 + ni * 16 + fr) * 64 + fq * 16);
    #pragma unroll
    for (int mi = 0; mi < 4; ++mi)
      #pragma unroll
      for (int ni = 0; ni < 4; ++ni)
        acc[mi][ni] = __builtin_amdgcn_mfma_f32_16x16x32_bf16(a[mi], b[ni], acc[mi][ni], 0, 0, 0);
    __syncthreads();
  }

  // ---- epilogue: add bias into acc, store bf16 ----
  #pragma unroll
  for (int ni = 0; ni < 4; ++ni) {
    int col = n0 + wc * 64 + ni * 16 + fr;
    float bvv = bias[col];
    #pragma unroll
    for (int mi = 0; mi < 4; ++mi)
      #pragma unroll
      for (int r = 0; r < 4; ++r)
        acc[mi][ni][r] += bvv;
  }
  #pragma unroll
  for (int ni = 0; ni < 4; ++ni) {
    int col = n0 + wc * 64 + ni * 16 + fr;
    #pragma unroll
    for (int mi = 0; mi < 4; ++mi) {
      #pragma unroll
      for (int r = 0; r < 4; ++r) {
        int row = m0 + wr * 64 + mi * 16 + fq * 4 + r;
        C[(size_t)row * DIM + col] = f2bf(acc[mi][ni][r]);
      }
    }
  }

  // ---- fused alpha logits (z==0): head h = n0/64 + wc ----
  if (z == 0) {
    const int h = (n0 >> 6) + wc;
    float qa0 = qalpha[h * HDIM + 0 * 16 + fr];
    float qa1 = qalpha[h * HDIM + 1 * 16 + fr];
    float qa2 = qalpha[h * HDIM + 2 * 16 + fr];
    float qa3 = qalpha[h * HDIM + 3 * 16 + fr];
    #pragma unroll
    for (int mi = 0; mi < 4; ++mi) {
      #pragma unroll
      for (int r = 0; r < 4; ++r) {
        float p = acc[mi][0][r] * qa0 + acc[mi][1][r] * qa1
                + acc[mi][2][r] * qa2 + acc[mi][3][r] * qa3;
        p += __shfl_xor(p, 1);
        p += __shfl_xor(p, 2);
        p += __shfl_xor(p, 4);
        p += __shfl_xor(p, 8);
        if (fr == 0) {
          int row = m0 + wr * 64 + mi * 16 + fq * 4 + r;
          la[((size_t)(row >> 12) * NHEAD + h) * SEQ + (row & (SEQ - 1))] = p * SCALEF;
        }
      }
    }
  }
}

// ---------------------------------------------------------------------------
// Softmax normalize l[bh][0..SEQ) in place (w = exp(x-m)/s); zero zbuf[bh][64].
// 64 blocks x 256 threads.
// ---------------------------------------------------------------------------
__global__ __launch_bounds__(256) void softmax_norm(
    float* __restrict__ l, float* __restrict__ zbuf)
{
  const int bh = blockIdx.x;
  const int tid = threadIdx.x, lane = tid & 63, wave = tid >> 6;
  float* p = l + (size_t)bh * SEQ;
  __shared__ float red[8];

  float4 v[4];
  #pragma unroll
  for (int i = 0; i < 4; ++i) v[i] = ((const float4*)p)[i * 256 + tid];

  float m = -1e30f;
  #pragma unroll
  for (int i = 0; i < 4; ++i)
    m = fmaxf(m, fmaxf(fmaxf(v[i].x, v[i].y), fmaxf(v[i].z, v[i].w)));
  #pragma unroll
  for (int o = 32; o; o >>= 1) m = fmaxf(m, __shfl_xor(m, o));
  if (lane == 0) red[wave] = m;
  __syncthreads();
  m = fmaxf(fmaxf(red[0], red[1]), fmaxf(red[2], red[3]));

  float s = 0.f;
  #pragma unroll
  for (int i = 0; i < 4; ++i) {
    v[i].x = __expf(v[i].x - m); v[i].y = __expf(v[i].y - m);
    v[i].z = __expf(v[i].z - m); v[i].w = __expf(v[i].w - m);
    s += (v[i].x + v[i].y) + (v[i].z + v[i].w);
  }
  #pragma unroll
  for (int o = 32; o; o >>= 1) s += __shfl_xor(s, o);
  if (lane == 0) red[4 + wave] = s;
  __syncthreads();
  s = (red[4] + red[5]) + (red[6] + red[7]);

  float inv = 1.0f / s;
  #pragma unroll
  for (int i = 0; i < 4; ++i) {
    v[i].x *= inv; v[i].y *= inv; v[i].z *= inv; v[i].w *= inv;
    ((float4*)p)[i * 256 + tid] = v[i];
  }
  if (tid < HDIM) zbuf[bh * HDIM + tid] = 0.f;
}

// ---------------------------------------------------------------------------
// outp[bh][d] += sum_n w[bh][n] * X[b][n][h*64+d].  grid (8 chunks, 64 bh).
// ---------------------------------------------------------------------------
__global__ __launch_bounds__(256) void accum_weighted(
    const u16* __restrict__ X, const float* __restrict__ w,
    float* __restrict__ outp)
{
  const int bh = blockIdx.y, chunk = blockIdx.x;
  const int b = bh >> 4, h = bh & 15;
  const int tid = threadIdx.x, lane = tid & 63, wave = tid >> 6;
  const int rsub = lane >> 3, cl = lane & 7;
  const size_t base = (size_t)b * SEQ * DIM + h * HDIM;
  const int n0 = chunk * 512;

  float acc[8] = {0, 0, 0, 0, 0, 0, 0, 0};
  for (int it = 0; it < 16; ++it) {
    int n = n0 + it * 32 + wave * 8 + rsub;
    u16x8 u = *(const u16x8*)(X + base + (size_t)n * DIM + cl * 8);
    float wv = w[(size_t)bh * SEQ + n];
    #pragma unroll
    for (int j = 0; j < 8; ++j) acc[j] += wv * bf2f(u[j]);
  }
  #pragma unroll
  for (int j = 0; j < 8; ++j) {
    acc[j] += __shfl_xor(acc[j], 8);
    acc[j] += __shfl_xor(acc[j], 16);
    acc[j] += __shfl_xor(acc[j], 32);
  }
  __shared__ float part[4][64];
  if (rsub == 0) {
    #pragma unroll
    for (int j = 0; j < 8; ++j) part[wave][cl * 8 + j] = acc[j];
  }
  __syncthreads();
  if (tid < HDIM) {
    float s = (part[0][tid] + part[1][tid]) + (part[2][tid] + part[3][tid]);
    atomicAdd(&outp[bh * HDIM + tid], s);
  }
}

// ---------------------------------------------------------------------------
// vecb[bh][d] = gq[bh][d] * k_beta[h][d] * SCALE.  16 blocks.
// ---------------------------------------------------------------------------
__global__ __launch_bounds__(256) void make_vecb(
    const float* __restrict__ gq, const float* __restrict__ kbeta,
    float* __restrict__ vecb)
{
  int t = blockIdx.x * 256 + threadIdx.x;  // 0..4095
  int h = (t >> 6) & 15, d = t & 63;
  vecb[t] = gq[t] * kbeta[h * HDIM + d] * SCALEF;
}

// ---------------------------------------------------------------------------
// Beta logits: lb[b*16+h][n] = dot(K[b][n][h*64:+64], vecb[b*16+h]).
// 1024 blocks x 256 threads, 16 rows per block.
// ---------------------------------------------------------------------------
__global__ __launch_bounds__(256) void logits_beta(
    const u16* __restrict__ Kb, const float* __restrict__ vecb,
    float* __restrict__ lb)
{
  __shared__ float vb[NHEAD][HDIM];
  const int rg = blockIdx.x;           // 16 global rows per block
  const int b = rg >> 8;               // 256 blocks per batch
  const int tid = threadIdx.x, lane = tid & 63, wave = tid >> 6;

  for (int i = tid; i < NHEAD * HDIM; i += 256)
    ((float*)vb)[i] = vecb[b * DIM + i];
  __syncthreads();

  const int h = lane >> 2, dq = (lane & 3) * 16;
  #pragma unroll
  for (int i = 0; i < 4; ++i) {
    int gr = rg * 16 + wave * 4 + i;
    const u16* rp = Kb + (size_t)gr * DIM + h * HDIM + dq;
    u16x8 u0 = *(const u16x8*)rp;
    u16x8 u1 = *(const u16x8*)(rp + 8);
    float dot = 0.f;
    #pragma unroll
    for (int j = 0; j < 8; ++j) dot += bf2f(u0[j]) * vb[h][dq + j];
    #pragma unroll
    for (int j = 0; j < 8; ++j) dot += bf2f(u1[j]) * vb[h][dq + 8 + j];
    dot += __shfl_xor(dot, 1);
    dot += __shfl_xor(dot, 2);
    if ((lane & 3) == 0) {
      lb[((size_t)b * NHEAD + h) * SEQ + (gr & (SEQ - 1))] = dot;
    }
  }
}

// ---------------------------------------------------------------------------
// c2[b,j] = sum_k gv[b,k]*Wo[j,k] + bo[j].  One wave per (b,j); 1024 blocks.
// ---------------------------------------------------------------------------
__global__ __launch_bounds__(256) void gv_wo_kernel(
    const float* __restrict__ gv, const float* __restrict__ Wo,
    const float* __restrict__ bo, float* __restrict__ c2)
{
  int wid = blockIdx.x * 4 + (threadIdx.x >> 6);  // 0..4095 = b*1024 + j
  int b = wid >> 10, j = wid & 1023;
  int lane = threadIdx.x & 63;
  float acc = 0.f;
  #pragma unroll
  for (int c = 0; c < 16; ++c) {
    int kk = c * 64 + lane;
    acc += gv[b * DIM + kk] * Wo[(size_t)j * DIM + kk];
  }
  #pragma unroll
  for (int o = 32; o; o >>= 1) acc += __shfl_down(acc, o);
  if (lane == 0) c2[wid] = acc + bo[j];
}

// ---------------------------------------------------------------------------
// Output GEMM: out = Qb(bf16) @ Wo^T + c2[b]  (fp32 out).
// ---------------------------------------------------------------------------
__global__ __launch_bounds__(256) void gemm_out(
    const u16* __restrict__ Qb, const u16* __restrict__ Wo_bf,
    const float* __restrict__ c2, float* __restrict__ out)
{
  __shared__ __align__(16) u16 As[128 * 32];
  __shared__ __align__(16) u16 Bs[128 * 32];

  const int tid = threadIdx.x;
  const int lane = tid & 63, wave = tid >> 6;
  const int wr = wave >> 1, wc = wave & 1;
  const int fr = lane & 15, fq = lane >> 4;
  const int m0 = blockIdx.x * 128, n0 = blockIdx.y * 128;
  const int bidx = m0 >> 12;

  f32x4 acc[4][4];
  #pragma unroll
  for (int i = 0; i < 4; ++i)
    #pragma unroll
    for (int j = 0; j < 4; ++j) acc[i][j] = (f32x4){0.f, 0.f, 0.f, 0.f};

  for (int kt = 0; kt < DIM / 32; ++kt) {
    #pragma unroll
    for (int i = 0; i < 2; ++i) {
      int ci = i * 256 + wave * 64 + lane;
      const u16* ga = Qb + (size_t)(m0 + (ci >> 2)) * DIM + kt * 32 + (ci & 3) * 8;
      gload_lds16(ga, (char*)As + (i * 256 + wave * 64) * 16);
      const u16* gb = Wo_bf + (size_t)(n0 + (ci >> 2)) * DIM + kt * 32 + (ci & 3) * 8;
      gload_lds16(gb, (char*)Bs + (i * 256 + wave * 64) * 16);
    }
    __syncthreads();
    s16x8 a[4], b[4];
    #pragma unroll
    for (int mi = 0; mi < 4; ++mi)
      a[mi] = *(const s16x8*)((const char*)As + (wr * 64 + mi * 16 + fr) * 64 + fq * 16);
    #pragma unroll
    for (int ni = 0; ni < 4; ++ni)
      b[ni] = *(const s16x8*)((const char*)Bs + (wc * 64 + ni * 16 + fr) * 64 + fq * 16);
    #pragma unroll
    for (int mi = 0; mi < 4; ++mi)
      #pragma unroll
      for (int ni = 0; ni < 4; ++ni)
        acc[mi][ni] = __builtin_amdgcn_mfma_f32_16x16x32_bf16(a[mi], b[ni], acc[mi][ni], 0, 0, 0);
    __syncthreads();
  }

  #pragma unroll
  for (int ni = 0; ni < 4; ++ni) {
    int col = n0 + wc * 64 + ni * 16 + fr;
    float cv = c2[bidx * DIM + col];
    #pragma unroll
    for (int mi = 0; mi < 4; ++mi) {
      #pragma unroll
      for (int r = 0; r < 4; ++r) {
        int row = m0 + wr * 64 + mi * 16 + fq * 4 + r;
        out[(size_t)row * DIM + col] = acc[mi][ni][r] + cv;
      }
    }
  }
}

// ---------------------------------------------------------------------------
extern "C" void kernel_launch(void* const* d_in, const int* in_sizes, int n_in,
                              void* d_out, int out_size, void* d_ws, size_t ws_size,
                              hipStream_t stream) {
  const float* q  = (const float*)d_in[0];
  const float* k  = (const float*)d_in[1];
  const float* v  = (const float*)d_in[2];
  const float* Wq = (const float*)d_in[3];
  const float* bq = (const float*)d_in[4];
  const float* Wk = (const float*)d_in[5];
  const float* bk = (const float*)d_in[6];
  const float* Wv = (const float*)d_in[7];
  const float* bv = (const float*)d_in[8];
  const float* qa = (const float*)d_in[9];
  const float* kb = (const float*)d_in[10];
  const float* Wo = (const float*)d_in[11];
  const float* bo = (const float*)d_in[12];
  float* out = (float*)d_out;

  // workspace layout (~106 MB)
  u16* Qb  = (u16*)d_ws;
  u16* Kb  = Qb + (size_t)MROWS * DIM;
  u16* Vb  = Kb + (size_t)MROWS * DIM;
  u16* Wqb = Vb + (size_t)MROWS * DIM;
  u16* Wkb = Wqb + (size_t)DIM * DIM;
  u16* Wvb = Wkb + (size_t)DIM * DIM;
  u16* Wob = Wvb + (size_t)DIM * DIM;
  float* la   = (float*)(Wob + (size_t)DIM * DIM);     // 64*4096 = 1MB
  float* lb   = la + (size_t)NB * NHEAD * SEQ;         // 1MB
  float* gq   = lb + (size_t)NB * NHEAD * SEQ;         // 16KB
  float* gv   = gq + NB * DIM;
  float* vecb = gv + NB * DIM;
  float* c2   = vecb + NB * DIM;

  cvt_weights<<<2048, 256, 0, stream>>>(Wq, Wk, Wv, Wo, Wqb, Wkb, Wvb, Wob);
  gemm_qkv<<<dim3(128, 8, 3), 256, 0, stream>>>(q, k, v, Wqb, Wkb, Wvb,
                                                bq, bk, bv, Qb, Kb, Vb, qa, la);
  softmax_norm<<<64, 256, 0, stream>>>(la, gq);                 // alpha weights, zero gq
  accum_weighted<<<dim3(8, 64), 256, 0, stream>>>(Qb, la, gq);  // global_q
  make_vecb<<<16, 256, 0, stream>>>(gq, kb, vecb);
  logits_beta<<<1024, 256, 0, stream>>>(Kb, vecb, lb);
  softmax_norm<<<64, 256, 0, stream>>>(lb, gv);                 // beta weights, zero gv
  accum_weighted<<<dim3(8, 64), 256, 0, stream>>>(Vb, lb, gv);  // global_v
  gv_wo_kernel<<<1024, 256, 0, stream>>>(gv, Wo, bo, c2);
  gemm_out<<<dim3(128, 8, 1), 256, 0, stream>>>(Qb, Wob, c2, out);
}

// Round 3
// 359.584 us; speedup vs baseline: 1.5766x; 1.0173x over previous
//
#include <hip/hip_runtime.h>
#include <hip/hip_bf16.h>
#include <cstdint>
#include <cstddef>

// Problem constants
#define SEQ    4096
#define NB     4
#define DIM    1024
#define NHEAD  16
#define HDIM   64
#define MROWS  (NB * SEQ)   // 16384
#define SCALEF 0.125f       // 64^-0.5

typedef short          s16x8 __attribute__((ext_vector_type(8)));
typedef unsigned short u16x8 __attribute__((ext_vector_type(8)));
typedef float          f32x4 __attribute__((ext_vector_type(4)));
typedef unsigned short u16;

// HW convert (compiler emits v_cvt_pk_bf16_f32 for pairs — do NOT hand-roll RNE,
// the bit-twiddle version costs ~4 VALU ops/element and was 32% VALUBusy in r2).
__device__ __forceinline__ u16 f2bf(float f) {
  return __builtin_bit_cast(u16, __float2bfloat16(f));
}
__device__ __forceinline__ float bf2f(u16 u) {
  return __builtin_bit_cast(float, (uint32_t)u << 16);
}
__device__ __forceinline__ void gload_lds16(const void* g, void* l) {
  __builtin_amdgcn_global_load_lds(
      (const __attribute__((address_space(1))) void*)g,
      (__attribute__((address_space(3))) void*)l, 16, 0, 0);
}

// ---------------------------------------------------------------------------
// Convert the four [DIM,DIM] fp32 weight matrices to bf16.
// ---------------------------------------------------------------------------
__global__ __launch_bounds__(256) void cvt_weights(
    const float* __restrict__ w0, const float* __restrict__ w1,
    const float* __restrict__ w2, const float* __restrict__ w3,
    u16* __restrict__ o0, u16* __restrict__ o1,
    u16* __restrict__ o2, u16* __restrict__ o3)
{
  int t = blockIdx.x * 256 + threadIdx.x;        // 0 .. 524287
  int m = t >> 17;                               // which matrix
  int off = (t & 131071) * 8;                    // 8 floats per thread
  const float* s = (m == 0) ? w0 : (m == 1) ? w1 : (m == 2) ? w2 : w3;
  u16*         d = (m == 0) ? o0 : (m == 1) ? o1 : (m == 2) ? o2 : o3;
  float4 a = ((const float4*)(s + off))[0];
  float4 b = ((const float4*)(s + off))[1];
  u16x8 p;
  p[0] = f2bf(a.x); p[1] = f2bf(a.y); p[2] = f2bf(a.z); p[3] = f2bf(a.w);
  p[4] = f2bf(b.x); p[5] = f2bf(b.y); p[6] = f2bf(b.z); p[7] = f2bf(b.w);
  *(u16x8*)(d + off) = p;
}

// ---------------------------------------------------------------------------
// QKV projection GEMM: C = A(fp32) @ W^T + bias, C stored bf16.
// 128x128 tile, BK=32, 4 waves (2x2 of 64x64), mfma_f32_16x16x32_bf16.
// z==0 additionally emits alpha logits la[b*16+h][n] (fused: the wave's
// fr-group holds the full 64-d head slice of each Q row).
// ---------------------------------------------------------------------------
__global__ __launch_bounds__(256) void gemm_qkv(
    const float* __restrict__ qin, const float* __restrict__ kin, const float* __restrict__ vin,
    const u16* __restrict__ Wq, const u16* __restrict__ Wk, const u16* __restrict__ Wv,
    const float* __restrict__ bq, const float* __restrict__ bk, const float* __restrict__ bv,
    u16* __restrict__ Qo, u16* __restrict__ Ko, u16* __restrict__ Vo,
    const float* __restrict__ qalpha, float* __restrict__ la)
{
  __shared__ __align__(16) u16 As[128 * 32];   // [row][k] k-contig, 8KB
  __shared__ __align__(16) u16 Bs[128 * 32];   // [outcol][k] k-contig, 8KB

  const int z = blockIdx.z;
  const float* A    = (z == 0) ? qin : (z == 1) ? kin : vin;
  const u16*   W    = (z == 0) ? Wq  : (z == 1) ? Wk  : Wv;
  const float* bias = (z == 0) ? bq  : (z == 1) ? bk  : bv;
  u16*         C    = (z == 0) ? Qo  : (z == 1) ? Ko  : Vo;

  const int tid = threadIdx.x;
  const int lane = tid & 63, wave = tid >> 6;
  const int wr = wave >> 1, wc = wave & 1;
  const int fr = lane & 15, fq = lane >> 4;
  const int m0 = blockIdx.x * 128, n0 = blockIdx.y * 128;

  const int sr = tid >> 1, sh = tid & 1;   // A staging: row, half(16 floats)
  const float* ag = A + (size_t)(m0 + sr) * DIM + sh * 16;

  f32x4 acc[4][4];
  #pragma unroll
  for (int i = 0; i < 4; ++i)
    #pragma unroll
    for (int j = 0; j < 4; ++j) acc[i][j] = (f32x4){0.f, 0.f, 0.f, 0.f};

  for (int kt = 0; kt < DIM / 32; ++kt) {
    #pragma unroll
    for (int i = 0; i < 2; ++i) {
      int ci = i * 256 + wave * 64 + lane;                   // 16B chunk id
      const u16* g = W + (size_t)(n0 + (ci >> 2)) * DIM + kt * 32 + (ci & 3) * 8;
      gload_lds16(g, (char*)Bs + (i * 256 + wave * 64) * 16);
    }
    {
      const float* ga = ag + kt * 32;
      float4 v0 = ((const float4*)ga)[0];
      float4 v1 = ((const float4*)ga)[1];
      float4 v2 = ((const float4*)ga)[2];
      float4 v3 = ((const float4*)ga)[3];
      u16x8 p0, p1;
      p0[0] = f2bf(v0.x); p0[1] = f2bf(v0.y); p0[2] = f2bf(v0.z); p0[3] = f2bf(v0.w);
      p0[4] = f2bf(v1.x); p0[5] = f2bf(v1.y); p0[6] = f2bf(v1.z); p0[7] = f2bf(v1.w);
      p1[0] = f2bf(v2.x); p1[1] = f2bf(v2.y); p1[2] = f2bf(v2.z); p1[3] = f2bf(v2.w);
      p1[4] = f2bf(v3.x); p1[5] = f2bf(v3.y); p1[6] = f2bf(v3.z); p1[7] = f2bf(v3.w);
      *(u16x8*)((char*)As + sr * 64 + sh * 32)      = p0;
      *(u16x8*)((char*)As + sr * 64 + sh * 32 + 16) = p1;
    }
    __syncthreads();
    s16x8 a[4], b[4];
    #pragma unroll
    for (int mi = 0; mi < 4; ++mi)
      a[mi] = *(const s16x8*)((const char*)As + (wr * 64 + mi * 16 + fr) * 64 + fq * 16);
    #pragma unroll
    for (int ni = 0; ni < 4; ++ni)
      b[ni] = *(const s16x8*)((const char*)Bs + (wc * 64 + ni * 16 + fr) * 64 + fq * 16);
    #pragma unroll
    for (int mi = 0; mi < 4; ++mi)
      #pragma unroll
      for (int ni = 0; ni < 4; ++ni)
        acc[mi][ni] = __builtin_amdgcn_mfma_f32_16x16x32_bf16(a[mi], b[ni], acc[mi][ni], 0, 0, 0);
    __syncthreads();
  }

  // ---- epilogue: add bias into acc, store bf16 ----
  #pragma unroll
  for (int ni = 0; ni < 4; ++ni) {
    int col = n0 + wc * 64 + ni * 16 + fr;
    float bvv = bias[col];
    #pragma unroll
    for (int mi = 0; mi < 4; ++mi)
      #pragma unroll
      for (int r = 0; r < 4; ++r)
        acc[mi][ni][r] += bvv;
  }
  #pragma unroll
  for (int ni = 0; ni < 4; ++ni) {
    int col = n0 + wc * 64 + ni * 16 + fr;
    #pragma unroll
    for (int mi = 0; mi < 4; ++mi) {
      #pragma unroll
      for (int r = 0; r < 4; ++r) {
        int row = m0 + wr * 64 + mi * 16 + fq * 4 + r;
        C[(size_t)row * DIM + col] = f2bf(acc[mi][ni][r]);
      }
    }
  }

  // ---- fused alpha logits (z==0): head h = n0/64 + wc ----
  if (z == 0) {
    const int h = (n0 >> 6) + wc;
    float qa0 = qalpha[h * HDIM + 0 * 16 + fr];
    float qa1 = qalpha[h * HDIM + 1 * 16 + fr];
    float qa2 = qalpha[h * HDIM + 2 * 16 + fr];
    float qa3 = qalpha[h * HDIM + 3 * 16 + fr];
    #pragma unroll
    for (int mi = 0; mi < 4; ++mi) {
      #pragma unroll
      for (int r = 0; r < 4; ++r) {
        float p = acc[mi][0][r] * qa0 + acc[mi][1][r] * qa1
                + acc[mi][2][r] * qa2 + acc[mi][3][r] * qa3;
        p += __shfl_xor(p, 1);
        p += __shfl_xor(p, 2);
        p += __shfl_xor(p, 4);
        p += __shfl_xor(p, 8);
        if (fr == 0) {
          int row = m0 + wr * 64 + mi * 16 + fq * 4 + r;
          la[((size_t)(row >> 12) * NHEAD + h) * SEQ + (row & (SEQ - 1))] = p * SCALEF;
        }
      }
    }
  }
}

// ---------------------------------------------------------------------------
// Softmax normalize l[bh][0..SEQ) in place (w = exp(x-m)/s); zero zbuf[bh][64].
// 64 blocks x 256 threads.
// ---------------------------------------------------------------------------
__global__ __launch_bounds__(256) void softmax_norm(
    float* __restrict__ l, float* __restrict__ zbuf)
{
  const int bh = blockIdx.x;
  const int tid = threadIdx.x, lane = tid & 63, wave = tid >> 6;
  float* p = l + (size_t)bh * SEQ;
  __shared__ float red[8];

  float4 v[4];
  #pragma unroll
  for (int i = 0; i < 4; ++i) v[i] = ((const float4*)p)[i * 256 + tid];

  float m = -1e30f;
  #pragma unroll
  for (int i = 0; i < 4; ++i)
    m = fmaxf(m, fmaxf(fmaxf(v[i].x, v[i].y), fmaxf(v[i].z, v[i].w)));
  #pragma unroll
  for (int o = 32; o; o >>= 1) m = fmaxf(m, __shfl_xor(m, o));
  if (lane == 0) red[wave] = m;
  __syncthreads();
  m = fmaxf(fmaxf(red[0], red[1]), fmaxf(red[2], red[3]));

  float s = 0.f;
  #pragma unroll
  for (int i = 0; i < 4; ++i) {
    v[i].x = __expf(v[i].x - m); v[i].y = __expf(v[i].y - m);
    v[i].z = __expf(v[i].z - m); v[i].w = __expf(v[i].w - m);
    s += (v[i].x + v[i].y) + (v[i].z + v[i].w);
  }
  #pragma unroll
  for (int o = 32; o; o >>= 1) s += __shfl_xor(s, o);
  if (lane == 0) red[4 + wave] = s;
  __syncthreads();
  s = (red[4] + red[5]) + (red[6] + red[7]);

  float inv = 1.0f / s;
  #pragma unroll
  for (int i = 0; i < 4; ++i) {
    v[i].x *= inv; v[i].y *= inv; v[i].z *= inv; v[i].w *= inv;
    ((float4*)p)[i * 256 + tid] = v[i];
  }
  if (tid < HDIM) zbuf[bh * HDIM + tid] = 0.f;
}

// ---------------------------------------------------------------------------
// outp[bh][d] += sum_n w[bh][n] * X[b][n][h*64+d].  grid (8 chunks, 64 bh).
// ---------------------------------------------------------------------------
__global__ __launch_bounds__(256) void accum_weighted(
    const u16* __restrict__ X, const float* __restrict__ w,
    float* __restrict__ outp)
{
  const int bh = blockIdx.y, chunk = blockIdx.x;
  const int b = bh >> 4, h = bh & 15;
  const int tid = threadIdx.x, lane = tid & 63, wave = tid >> 6;
  const int rsub = lane >> 3, cl = lane & 7;
  const size_t base = (size_t)b * SEQ * DIM + h * HDIM;
  const int n0 = chunk * 512;

  float acc[8] = {0, 0, 0, 0, 0, 0, 0, 0};
  for (int it = 0; it < 16; ++it) {
    int n = n0 + it * 32 + wave * 8 + rsub;
    u16x8 u = *(const u16x8*)(X + base + (size_t)n * DIM + cl * 8);
    float wv = w[(size_t)bh * SEQ + n];
    #pragma unroll
    for (int j = 0; j < 8; ++j) acc[j] += wv * bf2f(u[j]);
  }
  #pragma unroll
  for (int j = 0; j < 8; ++j) {
    acc[j] += __shfl_xor(acc[j], 8);
    acc[j] += __shfl_xor(acc[j], 16);
    acc[j] += __shfl_xor(acc[j], 32);
  }
  __shared__ float part[4][64];
  if (rsub == 0) {
    #pragma unroll
    for (int j = 0; j < 8; ++j) part[wave][cl * 8 + j] = acc[j];
  }
  __syncthreads();
  if (tid < HDIM) {
    float s = (part[0][tid] + part[1][tid]) + (part[2][tid] + part[3][tid]);
    atomicAdd(&outp[bh * HDIM + tid], s);
  }
}

// ---------------------------------------------------------------------------
// vecb[bh][d] = gq[bh][d] * k_beta[h][d] * SCALE.  16 blocks.
// ---------------------------------------------------------------------------
__global__ __launch_bounds__(256) void make_vecb(
    const float* __restrict__ gq, const float* __restrict__ kbeta,
    float* __restrict__ vecb)
{
  int t = blockIdx.x * 256 + threadIdx.x;  // 0..4095
  int h = (t >> 6) & 15, d = t & 63;
  vecb[t] = gq[t] * kbeta[h * HDIM + d] * SCALEF;
}

// ---------------------------------------------------------------------------
// Beta logits: lb[b*16+h][n] = dot(K[b][n][h*64:+64], vecb[b*16+h]).
// 1024 blocks x 256 threads, 16 rows per block.
// ---------------------------------------------------------------------------
__global__ __launch_bounds__(256) void logits_beta(
    const u16* __restrict__ Kb, const float* __restrict__ vecb,
    float* __restrict__ lb)
{
  __shared__ float vb[NHEAD][HDIM];
  const int rg = blockIdx.x;           // 16 global rows per block
  const int b = rg >> 8;               // 256 blocks per batch
  const int tid = threadIdx.x, lane = tid & 63, wave = tid >> 6;

  for (int i = tid; i < NHEAD * HDIM; i += 256)
    ((float*)vb)[i] = vecb[b * DIM + i];
  __syncthreads();

  const int h = lane >> 2, dq = (lane & 3) * 16;
  #pragma unroll
  for (int i = 0; i < 4; ++i) {
    int gr = rg * 16 + wave * 4 + i;
    const u16* rp = Kb + (size_t)gr * DIM + h * HDIM + dq;
    u16x8 u0 = *(const u16x8*)rp;
    u16x8 u1 = *(const u16x8*)(rp + 8);
    float dot = 0.f;
    #pragma unroll
    for (int j = 0; j < 8; ++j) dot += bf2f(u0[j]) * vb[h][dq + j];
    #pragma unroll
    for (int j = 0; j < 8; ++j) dot += bf2f(u1[j]) * vb[h][dq + 8 + j];
    dot += __shfl_xor(dot, 1);
    dot += __shfl_xor(dot, 2);
    if ((lane & 3) == 0) {
      lb[((size_t)b * NHEAD + h) * SEQ + (gr & (SEQ - 1))] = dot;
    }
  }
}

// ---------------------------------------------------------------------------
// c2[b,j] = sum_k gv[b,k]*Wo[j,k] + bo[j].  One wave per (b,j); 1024 blocks.
// ---------------------------------------------------------------------------
__global__ __launch_bounds__(256) void gv_wo_kernel(
    const float* __restrict__ gv, const float* __restrict__ Wo,
    const float* __restrict__ bo, float* __restrict__ c2)
{
  int wid = blockIdx.x * 4 + (threadIdx.x >> 6);  // 0..4095 = b*1024 + j
  int b = wid >> 10, j = wid & 1023;
  int lane = threadIdx.x & 63;
  float acc = 0.f;
  #pragma unroll
  for (int c = 0; c < 16; ++c) {
    int kk = c * 64 + lane;
    acc += gv[b * DIM + kk] * Wo[(size_t)j * DIM + kk];
  }
  #pragma unroll
  for (int o = 32; o; o >>= 1) acc += __shfl_down(acc, o);
  if (lane == 0) c2[wid] = acc + bo[j];
}

// ---------------------------------------------------------------------------
// Output GEMM: out = Qb(bf16) @ Wo^T + c2[b]  (fp32 out).
// ---------------------------------------------------------------------------
__global__ __launch_bounds__(256) void gemm_out(
    const u16* __restrict__ Qb, const u16* __restrict__ Wo_bf,
    const float* __restrict__ c2, float* __restrict__ out)
{
  __shared__ __align__(16) u16 As[128 * 32];
  __shared__ __align__(16) u16 Bs[128 * 32];

  const int tid = threadIdx.x;
  const int lane = tid & 63, wave = tid >> 6;
  const int wr = wave >> 1, wc = wave & 1;
  const int fr = lane & 15, fq = lane >> 4;
  const int m0 = blockIdx.x * 128, n0 = blockIdx.y * 128;
  const int bidx = m0 >> 12;

  f32x4 acc[4][4];
  #pragma unroll
  for (int i = 0; i < 4; ++i)
    #pragma unroll
    for (int j = 0; j < 4; ++j) acc[i][j] = (f32x4){0.f, 0.f, 0.f, 0.f};

  for (int kt = 0; kt < DIM / 32; ++kt) {
    #pragma unroll
    for (int i = 0; i < 2; ++i) {
      int ci = i * 256 + wave * 64 + lane;
      const u16* ga = Qb + (size_t)(m0 + (ci >> 2)) * DIM + kt * 32 + (ci & 3) * 8;
      gload_lds16(ga, (char*)As + (i * 256 + wave * 64) * 16);
      const u16* gb = Wo_bf + (size_t)(n0 + (ci >> 2)) * DIM + kt * 32 + (ci & 3) * 8;
      gload_lds16(gb, (char*)Bs + (i * 256 + wave * 64) * 16);
    }
    __syncthreads();
    s16x8 a[4], b[4];
    #pragma unroll
    for (int mi = 0; mi < 4; ++mi)
      a[mi] = *(const s16x8*)((const char*)As + (wr * 64 + mi * 16 + fr) * 64 + fq * 16);
    #pragma unroll
    for (int ni = 0; ni < 4; ++ni)
      b[ni] = *(const s16x8*)((const char*)Bs + (wc * 64 + ni * 16 + fr) * 64 + fq * 16);
    #pragma unroll
    for (int mi = 0; mi < 4; ++mi)
      #pragma unroll
      for (int ni = 0; ni < 4; ++ni)
        acc[mi][ni] = __builtin_amdgcn_mfma_f32_16x16x32_bf16(a[mi], b[ni], acc[mi][ni], 0, 0, 0);
    __syncthreads();
  }

  #pragma unroll
  for (int ni = 0; ni < 4; ++ni) {
    int col = n0 + wc * 64 + ni * 16 + fr;
    float cv = c2[bidx * DIM + col];
    #pragma unroll
    for (int mi = 0; mi < 4; ++mi) {
      #pragma unroll
      for (int r = 0; r < 4; ++r) {
        int row = m0 + wr * 64 + mi * 16 + fq * 4 + r;
        out[(size_t)row * DIM + col] = acc[mi][ni][r] + cv;
      }
    }
  }
}

// ---------------------------------------------------------------------------
extern "C" void kernel_launch(void* const* d_in, const int* in_sizes, int n_in,
                              void* d_out, int out_size, void* d_ws, size_t ws_size,
                              hipStream_t stream) {
  const float* q  = (const float*)d_in[0];
  const float* k  = (const float*)d_in[1];
  const float* v  = (const float*)d_in[2];
  const float* Wq = (const float*)d_in[3];
  const float* bq = (const float*)d_in[4];
  const float* Wk = (const float*)d_in[5];
  const float* bk = (const float*)d_in[6];
  const float* Wv = (const float*)d_in[7];
  const float* bv = (const float*)d_in[8];
  const float* qa = (const float*)d_in[9];
  const float* kb = (const float*)d_in[10];
  const float* Wo = (const float*)d_in[11];
  const float* bo = (const float*)d_in[12];
  float* out = (float*)d_out;

  // workspace layout (~106 MB)
  u16* Qb  = (u16*)d_ws;
  u16* Kb  = Qb + (size_t)MROWS * DIM;
  u16* Vb  = Kb + (size_t)MROWS * DIM;
  u16* Wqb = Vb + (size_t)MROWS * DIM;
  u16* Wkb = Wqb + (size_t)DIM * DIM;
  u16* Wvb = Wkb + (size_t)DIM * DIM;
  u16* Wob = Wvb + (size_t)DIM * DIM;
  float* la   = (float*)(Wob + (size_t)DIM * DIM);     // 64*4096 = 1MB
  float* lb   = la + (size_t)NB * NHEAD * SEQ;         // 1MB
  float* gq   = lb + (size_t)NB * NHEAD * SEQ;         // 16KB
  float* gv   = gq + NB * DIM;
  float* vecb = gv + NB * DIM;
  float* c2   = vecb + NB * DIM;

  cvt_weights<<<2048, 256, 0, stream>>>(Wq, Wk, Wv, Wo, Wqb, Wkb, Wvb, Wob);
  gemm_qkv<<<dim3(128, 8, 3), 256, 0, stream>>>(q, k, v, Wqb, Wkb, Wvb,
                                                bq, bk, bv, Qb, Kb, Vb, qa, la);
  softmax_norm<<<64, 256, 0, stream>>>(la, gq);                 // alpha weights, zero gq
  accum_weighted<<<dim3(8, 64), 256, 0, stream>>>(Qb, la, gq);  // global_q
  make_vecb<<<16, 256, 0, stream>>>(gq, kb, vecb);
  logits_beta<<<1024, 256, 0, stream>>>(Kb, vecb, lb);
  softmax_norm<<<64, 256, 0, stream>>>(lb, gv);                 // beta weights, zero gv
  accum_weighted<<<dim3(8, 64), 256, 0, stream>>>(Vb, lb, gv);  // global_v
  gv_wo_kernel<<<1024, 256, 0, stream>>>(gv, Wo, bo, c2);
  gemm_out<<<dim3(128, 8, 1), 256, 0, stream>>>(Qb, Wob, c2, out);
}

// Round 4
// 311.034 us; speedup vs baseline: 1.8227x; 1.1561x over previous
//
#include <hip/hip_runtime.h>
#include <hip/hip_bf16.h>
#include <cstdint>
#include <cstddef>

// Problem constants
#define SEQ    4096
#define NB     4
#define DIM    1024
#define NHEAD  16
#define HDIM   64
#define MROWS  (NB * SEQ)   // 16384
#define SCALEF 0.125f       // 64^-0.5

typedef short          s16x8 __attribute__((ext_vector_type(8)));
typedef unsigned short u16x8 __attribute__((ext_vector_type(8)));
typedef float          f32x4 __attribute__((ext_vector_type(4)));
typedef unsigned short u16;

__device__ __forceinline__ u16 f2bf(float f) {
  return __builtin_bit_cast(u16, __float2bfloat16(f));
}
__device__ __forceinline__ float bf2f(u16 u) {
  return __builtin_bit_cast(float, (uint32_t)u << 16);
}
__device__ __forceinline__ void gload_lds16(const void* g, void* l) {
  __builtin_amdgcn_global_load_lds(
      (const __attribute__((address_space(1))) void*)g,
      (__attribute__((address_space(3))) void*)l, 16, 0, 0);
}

// ---------------------------------------------------------------------------
// Convert the four [DIM,DIM] fp32 weight matrices to bf16.
// ---------------------------------------------------------------------------
__global__ __launch_bounds__(256) void cvt_weights(
    const float* __restrict__ w0, const float* __restrict__ w1,
    const float* __restrict__ w2, const float* __restrict__ w3,
    u16* __restrict__ o0, u16* __restrict__ o1,
    u16* __restrict__ o2, u16* __restrict__ o3)
{
  int t = blockIdx.x * 256 + threadIdx.x;        // 0 .. 524287
  int m = t >> 17;                               // which matrix
  int off = (t & 131071) * 8;                    // 8 floats per thread
  const float* s = (m == 0) ? w0 : (m == 1) ? w1 : (m == 2) ? w2 : w3;
  u16*         d = (m == 0) ? o0 : (m == 1) ? o1 : (m == 2) ? o2 : o3;
  float4 a = ((const float4*)(s + off))[0];
  float4 b = ((const float4*)(s + off))[1];
  u16x8 p;
  p[0] = f2bf(a.x); p[1] = f2bf(a.y); p[2] = f2bf(a.z); p[3] = f2bf(a.w);
  p[4] = f2bf(b.x); p[5] = f2bf(b.y); p[6] = f2bf(b.z); p[7] = f2bf(b.w);
  *(u16x8*)(d + off) = p;
}

// ---------------------------------------------------------------------------
// Convert one [MROWS,DIM] fp32 activation matrix to bf16. 8192 blocks.
// ---------------------------------------------------------------------------
__global__ __launch_bounds__(256) void cvt_act(
    const float* __restrict__ s, u16* __restrict__ d)
{
  int t = blockIdx.x * 256 + threadIdx.x;        // 0 .. 2^21-1
  int off = t * 8;
  float4 a = ((const float4*)(s + off))[0];
  float4 b = ((const float4*)(s + off))[1];
  u16x8 p;
  p[0] = f2bf(a.x); p[1] = f2bf(a.y); p[2] = f2bf(a.z); p[3] = f2bf(a.w);
  p[4] = f2bf(b.x); p[5] = f2bf(b.y); p[6] = f2bf(b.z); p[7] = f2bf(b.w);
  *(u16x8*)(d + off) = p;
}

// ---------------------------------------------------------------------------
// Projection GEMM (m97 structure): C = A(bf16) @ W^T + bias, C stored bf16.
// Both operands via global_load_lds. 128x128 tile, BK=32, 4 waves.
// do_alpha!=0 additionally emits alpha logits la[b*16+h][n].
// ---------------------------------------------------------------------------
__global__ __launch_bounds__(256) void gemm_one(
    const u16* __restrict__ A, const u16* __restrict__ W,
    const float* __restrict__ bias, u16* __restrict__ C,
    int do_alpha, const float* __restrict__ qalpha, float* __restrict__ la)
{
  __shared__ __align__(16) u16 As[128 * 32];   // [row][k] k-contig, 8KB
  __shared__ __align__(16) u16 Bs[128 * 32];   // [outcol][k] k-contig, 8KB

  const int tid = threadIdx.x;
  const int lane = tid & 63, wave = tid >> 6;
  const int wr = wave >> 1, wc = wave & 1;
  const int fr = lane & 15, fq = lane >> 4;
  const int m0 = blockIdx.x * 128, n0 = blockIdx.y * 128;

  f32x4 acc[4][4];
  #pragma unroll
  for (int i = 0; i < 4; ++i)
    #pragma unroll
    for (int j = 0; j < 4; ++j) acc[i][j] = (f32x4){0.f, 0.f, 0.f, 0.f};

  for (int kt = 0; kt < DIM / 32; ++kt) {
    #pragma unroll
    for (int i = 0; i < 2; ++i) {
      int ci = i * 256 + wave * 64 + lane;                   // 16B chunk id
      const u16* ga = A + (size_t)(m0 + (ci >> 2)) * DIM + kt * 32 + (ci & 3) * 8;
      gload_lds16(ga, (char*)As + (i * 256 + wave * 64) * 16);
      const u16* gb = W + (size_t)(n0 + (ci >> 2)) * DIM + kt * 32 + (ci & 3) * 8;
      gload_lds16(gb, (char*)Bs + (i * 256 + wave * 64) * 16);
    }
    __syncthreads();
    s16x8 a[4], b[4];
    #pragma unroll
    for (int mi = 0; mi < 4; ++mi)
      a[mi] = *(const s16x8*)((const char*)As + (wr * 64 + mi * 16 + fr) * 64 + fq * 16);
    #pragma unroll
    for (int ni = 0; ni < 4; ++ni)
      b[ni] = *(const s16x8*)((const char*)Bs + (wc * 64 + ni * 16 + fr) * 64 + fq * 16);
    #pragma unroll
    for (int mi = 0; mi < 4; ++mi)
      #pragma unroll
      for (int ni = 0; ni < 4; ++ni)
        acc[mi][ni] = __builtin_amdgcn_mfma_f32_16x16x32_bf16(a[mi], b[ni], acc[mi][ni], 0, 0, 0);
    __syncthreads();
  }

  // ---- epilogue: add bias into acc, store bf16 ----
  #pragma unroll
  for (int ni = 0; ni < 4; ++ni) {
    int col = n0 + wc * 64 + ni * 16 + fr;
    float bvv = bias[col];
    #pragma unroll
    for (int mi = 0; mi < 4; ++mi)
      #pragma unroll
      for (int r = 0; r < 4; ++r)
        acc[mi][ni][r] += bvv;
  }
  #pragma unroll
  for (int ni = 0; ni < 4; ++ni) {
    int col = n0 + wc * 64 + ni * 16 + fr;
    #pragma unroll
    for (int mi = 0; mi < 4; ++mi) {
      #pragma unroll
      for (int r = 0; r < 4; ++r) {
        int row = m0 + wr * 64 + mi * 16 + fq * 4 + r;
        C[(size_t)row * DIM + col] = f2bf(acc[mi][ni][r]);
      }
    }
  }

  // ---- fused alpha logits: head h = n0/64 + wc ----
  if (do_alpha) {
    const int h = (n0 >> 6) + wc;
    float qa0 = qalpha[h * HDIM + 0 * 16 + fr];
    float qa1 = qalpha[h * HDIM + 1 * 16 + fr];
    float qa2 = qalpha[h * HDIM + 2 * 16 + fr];
    float qa3 = qalpha[h * HDIM + 3 * 16 + fr];
    #pragma unroll
    for (int mi = 0; mi < 4; ++mi) {
      #pragma unroll
      for (int r = 0; r < 4; ++r) {
        float p = acc[mi][0][r] * qa0 + acc[mi][1][r] * qa1
                + acc[mi][2][r] * qa2 + acc[mi][3][r] * qa3;
        p += __shfl_xor(p, 1);
        p += __shfl_xor(p, 2);
        p += __shfl_xor(p, 4);
        p += __shfl_xor(p, 8);
        if (fr == 0) {
          int row = m0 + wr * 64 + mi * 16 + fq * 4 + r;
          la[((size_t)(row >> 12) * NHEAD + h) * SEQ + (row & (SEQ - 1))] = p * SCALEF;
        }
      }
    }
  }
}

// ---------------------------------------------------------------------------
// Softmax normalize l[bh][0..SEQ) in place (w = exp(x-m)/s); zero zbuf[bh][64].
// 64 blocks x 256 threads.
// ---------------------------------------------------------------------------
__global__ __launch_bounds__(256) void softmax_norm(
    float* __restrict__ l, float* __restrict__ zbuf)
{
  const int bh = blockIdx.x;
  const int tid = threadIdx.x, lane = tid & 63, wave = tid >> 6;
  float* p = l + (size_t)bh * SEQ;
  __shared__ float red[8];

  float4 v[4];
  #pragma unroll
  for (int i = 0; i < 4; ++i) v[i] = ((const float4*)p)[i * 256 + tid];

  float m = -1e30f;
  #pragma unroll
  for (int i = 0; i < 4; ++i)
    m = fmaxf(m, fmaxf(fmaxf(v[i].x, v[i].y), fmaxf(v[i].z, v[i].w)));
  #pragma unroll
  for (int o = 32; o; o >>= 1) m = fmaxf(m, __shfl_xor(m, o));
  if (lane == 0) red[wave] = m;
  __syncthreads();
  m = fmaxf(fmaxf(red[0], red[1]), fmaxf(red[2], red[3]));

  float s = 0.f;
  #pragma unroll
  for (int i = 0; i < 4; ++i) {
    v[i].x = __expf(v[i].x - m); v[i].y = __expf(v[i].y - m);
    v[i].z = __expf(v[i].z - m); v[i].w = __expf(v[i].w - m);
    s += (v[i].x + v[i].y) + (v[i].z + v[i].w);
  }
  #pragma unroll
  for (int o = 32; o; o >>= 1) s += __shfl_xor(s, o);
  if (lane == 0) red[4 + wave] = s;
  __syncthreads();
  s = (red[4] + red[5]) + (red[6] + red[7]);

  float inv = 1.0f / s;
  #pragma unroll
  for (int i = 0; i < 4; ++i) {
    v[i].x *= inv; v[i].y *= inv; v[i].z *= inv; v[i].w *= inv;
    ((float4*)p)[i * 256 + tid] = v[i];
  }
  if (tid < HDIM) zbuf[bh * HDIM + tid] = 0.f;
}

// ---------------------------------------------------------------------------
// outp[bh][d] += sum_n w[bh][n] * X[b][n][h*64+d].  grid (8 chunks, 64 bh).
// ---------------------------------------------------------------------------
__global__ __launch_bounds__(256) void accum_weighted(
    const u16* __restrict__ X, const float* __restrict__ w,
    float* __restrict__ outp)
{
  const int bh = blockIdx.y, chunk = blockIdx.x;
  const int b = bh >> 4, h = bh & 15;
  const int tid = threadIdx.x, lane = tid & 63, wave = tid >> 6;
  const int rsub = lane >> 3, cl = lane & 7;
  const size_t base = (size_t)b * SEQ * DIM + h * HDIM;
  const int n0 = chunk * 512;

  float acc[8] = {0, 0, 0, 0, 0, 0, 0, 0};
  for (int it = 0; it < 16; ++it) {
    int n = n0 + it * 32 + wave * 8 + rsub;
    u16x8 u = *(const u16x8*)(X + base + (size_t)n * DIM + cl * 8);
    float wv = w[(size_t)bh * SEQ + n];
    #pragma unroll
    for (int j = 0; j < 8; ++j) acc[j] += wv * bf2f(u[j]);
  }
  #pragma unroll
  for (int j = 0; j < 8; ++j) {
    acc[j] += __shfl_xor(acc[j], 8);
    acc[j] += __shfl_xor(acc[j], 16);
    acc[j] += __shfl_xor(acc[j], 32);
  }
  __shared__ float part[4][64];
  if (rsub == 0) {
    #pragma unroll
    for (int j = 0; j < 8; ++j) part[wave][cl * 8 + j] = acc[j];
  }
  __syncthreads();
  if (tid < HDIM) {
    float s = (part[0][tid] + part[1][tid]) + (part[2][tid] + part[3][tid]);
    atomicAdd(&outp[bh * HDIM + tid], s);
  }
}

// ---------------------------------------------------------------------------
// vecb[bh][d] = gq[bh][d] * k_beta[h][d] * SCALE.  16 blocks.
// ---------------------------------------------------------------------------
__global__ __launch_bounds__(256) void make_vecb(
    const float* __restrict__ gq, const float* __restrict__ kbeta,
    float* __restrict__ vecb)
{
  int t = blockIdx.x * 256 + threadIdx.x;  // 0..4095
  int h = (t >> 6) & 15, d = t & 63;
  vecb[t] = gq[t] * kbeta[h * HDIM + d] * SCALEF;
}

// ---------------------------------------------------------------------------
// Beta logits: lb[b*16+h][n] = dot(K[b][n][h*64:+64], vecb[b*16+h]).
// 1024 blocks x 256 threads, 16 rows per block.
// ---------------------------------------------------------------------------
__global__ __launch_bounds__(256) void logits_beta(
    const u16* __restrict__ Kb, const float* __restrict__ vecb,
    float* __restrict__ lb)
{
  __shared__ float vb[NHEAD][HDIM];
  const int rg = blockIdx.x;           // 16 global rows per block
  const int b = rg >> 8;               // 256 blocks per batch
  const int tid = threadIdx.x, lane = tid & 63, wave = tid >> 6;

  for (int i = tid; i < NHEAD * HDIM; i += 256)
    ((float*)vb)[i] = vecb[b * DIM + i];
  __syncthreads();

  const int h = lane >> 2, dq = (lane & 3) * 16;
  #pragma unroll
  for (int i = 0; i < 4; ++i) {
    int gr = rg * 16 + wave * 4 + i;
    const u16* rp = Kb + (size_t)gr * DIM + h * HDIM + dq;
    u16x8 u0 = *(const u16x8*)rp;
    u16x8 u1 = *(const u16x8*)(rp + 8);
    float dot = 0.f;
    #pragma unroll
    for (int j = 0; j < 8; ++j) dot += bf2f(u0[j]) * vb[h][dq + j];
    #pragma unroll
    for (int j = 0; j < 8; ++j) dot += bf2f(u1[j]) * vb[h][dq + 8 + j];
    dot += __shfl_xor(dot, 1);
    dot += __shfl_xor(dot, 2);
    if ((lane & 3) == 0) {
      lb[((size_t)b * NHEAD + h) * SEQ + (gr & (SEQ - 1))] = dot;
    }
  }
}

// ---------------------------------------------------------------------------
// c2[b,j] = sum_k gv[b,k]*Wo[j,k] + bo[j].  One wave per (b,j); 1024 blocks.
// ---------------------------------------------------------------------------
__global__ __launch_bounds__(256) void gv_wo_kernel(
    const float* __restrict__ gv, const float* __restrict__ Wo,
    const float* __restrict__ bo, float* __restrict__ c2)
{
  int wid = blockIdx.x * 4 + (threadIdx.x >> 6);  // 0..4095 = b*1024 + j
  int b = wid >> 10, j = wid & 1023;
  int lane = threadIdx.x & 63;
  float acc = 0.f;
  #pragma unroll
  for (int c = 0; c < 16; ++c) {
    int kk = c * 64 + lane;
    acc += gv[b * DIM + kk] * Wo[(size_t)j * DIM + kk];
  }
  #pragma unroll
  for (int o = 32; o; o >>= 1) acc += __shfl_down(acc, o);
  if (lane == 0) c2[wid] = acc + bo[j];
}

// ---------------------------------------------------------------------------
// Output GEMM: out = Qb(bf16) @ Wo^T + c2[b]  (fp32 out).
// ---------------------------------------------------------------------------
__global__ __launch_bounds__(256) void gemm_out(
    const u16* __restrict__ Qb, const u16* __restrict__ Wo_bf,
    const float* __restrict__ c2, float* __restrict__ out)
{
  __shared__ __align__(16) u16 As[128 * 32];
  __shared__ __align__(16) u16 Bs[128 * 32];

  const int tid = threadIdx.x;
  const int lane = tid & 63, wave = tid >> 6;
  const int wr = wave >> 1, wc = wave & 1;
  const int fr = lane & 15, fq = lane >> 4;
  const int m0 = blockIdx.x * 128, n0 = blockIdx.y * 128;
  const int bidx = m0 >> 12;

  f32x4 acc[4][4];
  #pragma unroll
  for (int i = 0; i < 4; ++i)
    #pragma unroll
    for (int j = 0; j < 4; ++j) acc[i][j] = (f32x4){0.f, 0.f, 0.f, 0.f};

  for (int kt = 0; kt < DIM / 32; ++kt) {
    #pragma unroll
    for (int i = 0; i < 2; ++i) {
      int ci = i * 256 + wave * 64 + lane;
      const u16* ga = Qb + (size_t)(m0 + (ci >> 2)) * DIM + kt * 32 + (ci & 3) * 8;
      gload_lds16(ga, (char*)As + (i * 256 + wave * 64) * 16);
      const u16* gb = Wo_bf + (size_t)(n0 + (ci >> 2)) * DIM + kt * 32 + (ci & 3) * 8;
      gload_lds16(gb, (char*)Bs + (i * 256 + wave * 64) * 16);
    }
    __syncthreads();
    s16x8 a[4], b[4];
    #pragma unroll
    for (int mi = 0; mi < 4; ++mi)
      a[mi] = *(const s16x8*)((const char*)As + (wr * 64 + mi * 16 + fr) * 64 + fq * 16);
    #pragma unroll
    for (int ni = 0; ni < 4; ++ni)
      b[ni] = *(const s16x8*)((const char*)Bs + (wc * 64 + ni * 16 + fr) * 64 + fq * 16);
    #pragma unroll
    for (int mi = 0; mi < 4; ++mi)
      #pragma unroll
      for (int ni = 0; ni < 4; ++ni)
        acc[mi][ni] = __builtin_amdgcn_mfma_f32_16x16x32_bf16(a[mi], b[ni], acc[mi][ni], 0, 0, 0);
    __syncthreads();
  }

  #pragma unroll
  for (int ni = 0; ni < 4; ++ni) {
    int col = n0 + wc * 64 + ni * 16 + fr;
    float cv = c2[bidx * DIM + col];
    #pragma unroll
    for (int mi = 0; mi < 4; ++mi) {
      #pragma unroll
      for (int r = 0; r < 4; ++r) {
        int row = m0 + wr * 64 + mi * 16 + fq * 4 + r;
        out[(size_t)row * DIM + col] = acc[mi][ni][r] + cv;
      }
    }
  }
}

// ---------------------------------------------------------------------------
extern "C" void kernel_launch(void* const* d_in, const int* in_sizes, int n_in,
                              void* d_out, int out_size, void* d_ws, size_t ws_size,
                              hipStream_t stream) {
  const float* q  = (const float*)d_in[0];
  const float* k  = (const float*)d_in[1];
  const float* v  = (const float*)d_in[2];
  const float* Wq = (const float*)d_in[3];
  const float* bq = (const float*)d_in[4];
  const float* Wk = (const float*)d_in[5];
  const float* bk = (const float*)d_in[6];
  const float* Wv = (const float*)d_in[7];
  const float* bv = (const float*)d_in[8];
  const float* qa = (const float*)d_in[9];
  const float* kb = (const float*)d_in[10];
  const float* Wo = (const float*)d_in[11];
  const float* bo = (const float*)d_in[12];
  float* out = (float*)d_out;

  // workspace layout (~111 MB, same as r3)
  u16* Qb  = (u16*)d_ws;
  u16* Kb  = Qb + (size_t)MROWS * DIM;
  u16* Vb  = Kb + (size_t)MROWS * DIM;
  u16* Wqb = Vb + (size_t)MROWS * DIM;
  u16* Wkb = Wqb + (size_t)DIM * DIM;
  u16* Wvb = Wkb + (size_t)DIM * DIM;
  u16* Wob = Wvb + (size_t)DIM * DIM;
  float* la   = (float*)(Wob + (size_t)DIM * DIM);     // 64*4096 = 1MB
  float* lb   = la + (size_t)NB * NHEAD * SEQ;         // 1MB
  float* gq   = lb + (size_t)NB * NHEAD * SEQ;         // 16KB
  float* gv   = gq + NB * DIM;
  float* vecb = gv + NB * DIM;
  float* c2   = vecb + NB * DIM;

  // bf16 activation staging buffer lives in d_out (67 MB, dead until gemm_out;
  // each graph replay rewrites it before reading — deterministic).
  u16* actb = (u16*)d_out;   // 33.5 MB needed, 67 MB available

  cvt_weights<<<2048, 256, 0, stream>>>(Wq, Wk, Wv, Wo, Wqb, Wkb, Wvb, Wob);

  cvt_act<<<8192, 256, 0, stream>>>(q, actb);
  gemm_one<<<dim3(128, 8), 256, 0, stream>>>(actb, Wqb, bq, Qb, 1, qa, la);
  cvt_act<<<8192, 256, 0, stream>>>(k, actb);
  gemm_one<<<dim3(128, 8), 256, 0, stream>>>(actb, Wkb, bk, Kb, 0, qa, la);
  cvt_act<<<8192, 256, 0, stream>>>(v, actb);
  gemm_one<<<dim3(128, 8), 256, 0, stream>>>(actb, Wvb, bv, Vb, 0, qa, la);

  softmax_norm<<<64, 256, 0, stream>>>(la, gq);                 // alpha weights, zero gq
  accum_weighted<<<dim3(8, 64), 256, 0, stream>>>(Qb, la, gq);  // global_q
  make_vecb<<<16, 256, 0, stream>>>(gq, kb, vecb);
  logits_beta<<<1024, 256, 0, stream>>>(Kb, vecb, lb);
  softmax_norm<<<64, 256, 0, stream>>>(lb, gv);                 // beta weights, zero gv
  accum_weighted<<<dim3(8, 64), 256, 0, stream>>>(Vb, lb, gv);  // global_v
  gv_wo_kernel<<<1024, 256, 0, stream>>>(gv, Wo, bo, c2);
  gemm_out<<<dim3(128, 8), 256, 0, stream>>>(Qb, Wob, c2, out);
}

// Round 5
// 308.300 us; speedup vs baseline: 1.8389x; 1.0089x over previous
//
#include <hip/hip_runtime.h>
#include <hip/hip_bf16.h>
#include <cstdint>
#include <cstddef>

// Problem constants
#define SEQ    4096
#define NB     4
#define DIM    1024
#define NHEAD  16
#define HDIM   64
#define MROWS  (NB * SEQ)   // 16384
#define SCALEF 0.125f       // 64^-0.5
#define NT     16           // K tiles of 64

typedef short          s16x8 __attribute__((ext_vector_type(8)));
typedef unsigned short u16x8 __attribute__((ext_vector_type(8)));
typedef float          f32x4 __attribute__((ext_vector_type(4)));
typedef unsigned short u16;

__device__ __forceinline__ u16 f2bf(float f) {
  return __builtin_bit_cast(u16, __float2bfloat16(f));
}
__device__ __forceinline__ float bf2f(u16 u) {
  return __builtin_bit_cast(float, (uint32_t)u << 16);
}
__device__ __forceinline__ void gload_lds16(const void* g, void* l) {
  __builtin_amdgcn_global_load_lds(
      (const __attribute__((address_space(1))) void*)g,
      (__attribute__((address_space(3))) void*)l, 16, 0, 0);
}

// ---------------------------------------------------------------------------
// Convert the four [DIM,DIM] fp32 weight matrices to bf16.
// ---------------------------------------------------------------------------
__global__ __launch_bounds__(256) void cvt_weights(
    const float* __restrict__ w0, const float* __restrict__ w1,
    const float* __restrict__ w2, const float* __restrict__ w3,
    u16* __restrict__ o0, u16* __restrict__ o1,
    u16* __restrict__ o2, u16* __restrict__ o3)
{
  int t = blockIdx.x * 256 + threadIdx.x;
  int m = t >> 17;
  int off = (t & 131071) * 8;
  const float* s = (m == 0) ? w0 : (m == 1) ? w1 : (m == 2) ? w2 : w3;
  u16*         d = (m == 0) ? o0 : (m == 1) ? o1 : (m == 2) ? o2 : o3;
  float4 a = ((const float4*)(s + off))[0];
  float4 b = ((const float4*)(s + off))[1];
  u16x8 p;
  p[0] = f2bf(a.x); p[1] = f2bf(a.y); p[2] = f2bf(a.z); p[3] = f2bf(a.w);
  p[4] = f2bf(b.x); p[5] = f2bf(b.y); p[6] = f2bf(b.z); p[7] = f2bf(b.w);
  *(u16x8*)(d + off) = p;
}

// ---------------------------------------------------------------------------
// Convert one [MROWS,DIM] fp32 activation matrix to bf16. 8192 blocks.
// ---------------------------------------------------------------------------
__global__ __launch_bounds__(256) void cvt_act(
    const float* __restrict__ s, u16* __restrict__ d)
{
  int t = blockIdx.x * 256 + threadIdx.x;
  int off = t * 8;
  float4 a = ((const float4*)(s + off))[0];
  float4 b = ((const float4*)(s + off))[1];
  u16x8 p;
  p[0] = f2bf(a.x); p[1] = f2bf(a.y); p[2] = f2bf(a.z); p[3] = f2bf(a.w);
  p[4] = f2bf(b.x); p[5] = f2bf(b.y); p[6] = f2bf(b.z); p[7] = f2bf(b.w);
  *(u16x8*)(d + off) = p;
}

// ---------------------------------------------------------------------------
// 256x256-tile phase-split GEMM (T3+T4+T5), BK=64, 8 waves (2M x 4N), 512 thr.
// LDS (dynamic 128KB): A[2][256][64] bf16 @0, B[2][256][64] bf16 @65536.
// Per K-tile: 4 quadrant phases; one half-tile staged per phase into the idle
// parity set (exception Ah0(t+2) -> current set, fenced by phase-2's barrier
// pair); raw s_barrier (no waitcnt drain); per-tile checkpoint vmcnt(2)
// (vmcnt(0) at t==NT-2 where the prefetch pipeline shortens).
// MODE 0: C = A@W^T + bias -> bf16 (+optional fused alpha logits).
// MODE 1: C = A@W^T + c2[batch] -> fp32.
// ---------------------------------------------------------------------------
template<int MODE>
__global__ __launch_bounds__(512) void gemm256(
    const u16* __restrict__ A, const u16* __restrict__ W,
    const float* __restrict__ bias, u16* __restrict__ Cb, float* __restrict__ Cf,
    const float* __restrict__ c2, int do_alpha,
    const float* __restrict__ qalpha, float* __restrict__ la)
{
  extern __shared__ __align__(16) char smem[];
  const int tid = threadIdx.x;
  const int lane = tid & 63, wave = tid >> 6;
  const int wr = wave >> 2, wc = wave & 3;          // 2 (M) x 4 (N)
  const int fr = lane & 15, fq = lane >> 4;
  const int m0 = blockIdx.x * 256, n0 = blockIdx.y * 256;
  const int wrow = wr * 128, wcol = wc * 64;

  const int arow = tid >> 3;            // staging row-within-half 0..63
  const int acol = (tid & 7) * 8;       // staging k element 0..56

  f32x4 acc[8][4];
  #pragma unroll
  for (int i = 0; i < 8; ++i)
    #pragma unroll
    for (int j = 0; j < 4; ++j) acc[i][j] = (f32x4){0.f, 0.f, 0.f, 0.f};

  auto stA = [&](int kt, int h) {
    const u16* g = A + (size_t)(m0 + h * 128) * DIM + kt * 64;
    char* l = smem + (kt & 1) * 32768 + h * 16384;
    gload_lds16(g + (size_t)arow * DIM + acol,        l + tid * 16);
    gload_lds16(g + (size_t)(64 + arow) * DIM + acol, l + 8192 + tid * 16);
  };
  auto stB = [&](int kt, int h) {
    const u16* g = W + (size_t)(n0 + h * 128) * DIM + kt * 64;
    char* l = smem + 65536 + (kt & 1) * 32768 + h * 16384;
    gload_lds16(g + (size_t)arow * DIM + acol,        l + tid * 16);
    gload_lds16(g + (size_t)(64 + arow) * DIM + acol, l + 8192 + tid * 16);
  };

  // ---- prologue: tile0 fully + Ah0(1); tile0 landed via vmcnt(2) ----
  stA(0, 0); stA(0, 1); stB(0, 0); stB(0, 1);
  stA(1, 0);
  asm volatile("s_waitcnt vmcnt(2)" ::: "memory");
  asm volatile("s_barrier" ::: "memory");

  for (int t = 0; t < NT; ++t) {
    const char* Abase = smem + (t & 1) * 32768;
    const char* Bbase = smem + 65536 + (t & 1) * 32768;
    s16x8 areg[4][2];
    #pragma unroll
    for (int p = 0; p < 4; ++p) {
      const int mq = p >> 1, nq = p & 1;
      // ds-reads for this quadrant
      s16x8 breg[2][2];
      #pragma unroll
      for (int j = 0; j < 2; ++j)
        #pragma unroll
        for (int ks = 0; ks < 2; ++ks)
          breg[j][ks] = *(const s16x8*)(Bbase +
              (size_t)(wcol + (nq * 2 + j) * 16 + fr) * 128 + ks * 64 + fq * 16);
      if (nq == 0) {
        #pragma unroll
        for (int i = 0; i < 4; ++i)
          #pragma unroll
          for (int ks = 0; ks < 2; ++ks)
            areg[i][ks] = *(const s16x8*)(Abase +
                (size_t)(wrow + (mq * 4 + i) * 16 + fr) * 128 + ks * 64 + fq * 16);
      }
      // stage one half-tile
      if (p == 0 && t + 1 < NT) stA(t + 1, 1);
      if (p == 1 && t + 1 < NT) stB(t + 1, 0);
      if (p == 2 && t + 1 < NT) stB(t + 1, 1);
      if (p == 3 && t + 2 < NT) stA(t + 2, 0);

      asm volatile("s_barrier" ::: "memory");
      __builtin_amdgcn_s_setprio(1);
      #pragma unroll
      for (int i = 0; i < 4; ++i)
        #pragma unroll
        for (int j = 0; j < 2; ++j)
          #pragma unroll
          for (int ks = 0; ks < 2; ++ks)
            acc[mq * 4 + i][nq * 2 + j] = __builtin_amdgcn_mfma_f32_16x16x32_bf16(
                areg[i][ks], breg[j][ks], acc[mq * 4 + i][nq * 2 + j], 0, 0, 0);
      __builtin_amdgcn_s_setprio(0);
      if (p < 3) {
        asm volatile("s_barrier" ::: "memory");
      } else {
        if (t == NT - 2) asm volatile("s_waitcnt vmcnt(0)" ::: "memory");
        else             asm volatile("s_waitcnt vmcnt(2)" ::: "memory");
        asm volatile("s_barrier" ::: "memory");
      }
    }
  }

  // ---- epilogue ----
  if constexpr (MODE == 0) {
    #pragma unroll
    for (int ni = 0; ni < 4; ++ni) {
      const int col = n0 + wcol + ni * 16 + fr;
      const float bvv = bias[col];
      #pragma unroll
      for (int mi = 0; mi < 8; ++mi)
        #pragma unroll
        for (int r = 0; r < 4; ++r)
          acc[mi][ni][r] += bvv;
    }
    #pragma unroll
    for (int ni = 0; ni < 4; ++ni) {
      const int col = n0 + wcol + ni * 16 + fr;
      #pragma unroll
      for (int mi = 0; mi < 8; ++mi) {
        #pragma unroll
        for (int r = 0; r < 4; ++r) {
          const int row = m0 + wrow + mi * 16 + fq * 4 + r;
          Cb[(size_t)row * DIM + col] = f2bf(acc[mi][ni][r]);
        }
      }
    }
    if (do_alpha) {
      const int h = (n0 >> 6) + wc;
      float qa0 = qalpha[h * HDIM + 0 * 16 + fr];
      float qa1 = qalpha[h * HDIM + 1 * 16 + fr];
      float qa2 = qalpha[h * HDIM + 2 * 16 + fr];
      float qa3 = qalpha[h * HDIM + 3 * 16 + fr];
      #pragma unroll
      for (int mi = 0; mi < 8; ++mi) {
        #pragma unroll
        for (int r = 0; r < 4; ++r) {
          float p = acc[mi][0][r] * qa0 + acc[mi][1][r] * qa1
                  + acc[mi][2][r] * qa2 + acc[mi][3][r] * qa3;
          p += __shfl_xor(p, 1);
          p += __shfl_xor(p, 2);
          p += __shfl_xor(p, 4);
          p += __shfl_xor(p, 8);
          if (fr == 0) {
            const int row = m0 + wrow + mi * 16 + fq * 4 + r;
            la[((size_t)(row >> 12) * NHEAD + h) * SEQ + (row & (SEQ - 1))] = p * SCALEF;
          }
        }
      }
    }
  } else {
    const int bidx = m0 >> 12;
    #pragma unroll
    for (int ni = 0; ni < 4; ++ni) {
      const int col = n0 + wcol + ni * 16 + fr;
      const float cv = c2[bidx * DIM + col];
      #pragma unroll
      for (int mi = 0; mi < 8; ++mi) {
        #pragma unroll
        for (int r = 0; r < 4; ++r) {
          const int row = m0 + wrow + mi * 16 + fq * 4 + r;
          Cf[(size_t)row * DIM + col] = acc[mi][ni][r] + cv;
        }
      }
    }
  }
}

// ---------------------------------------------------------------------------
// Softmax normalize l[bh][0..SEQ) in place; zero zbuf[bh][64]. 64 blocks.
// ---------------------------------------------------------------------------
__global__ __launch_bounds__(256) void softmax_norm(
    float* __restrict__ l, float* __restrict__ zbuf)
{
  const int bh = blockIdx.x;
  const int tid = threadIdx.x, lane = tid & 63, wave = tid >> 6;
  float* p = l + (size_t)bh * SEQ;
  __shared__ float red[8];

  float4 v[4];
  #pragma unroll
  for (int i = 0; i < 4; ++i) v[i] = ((const float4*)p)[i * 256 + tid];

  float m = -1e30f;
  #pragma unroll
  for (int i = 0; i < 4; ++i)
    m = fmaxf(m, fmaxf(fmaxf(v[i].x, v[i].y), fmaxf(v[i].z, v[i].w)));
  #pragma unroll
  for (int o = 32; o; o >>= 1) m = fmaxf(m, __shfl_xor(m, o));
  if (lane == 0) red[wave] = m;
  __syncthreads();
  m = fmaxf(fmaxf(red[0], red[1]), fmaxf(red[2], red[3]));

  float s = 0.f;
  #pragma unroll
  for (int i = 0; i < 4; ++i) {
    v[i].x = __expf(v[i].x - m); v[i].y = __expf(v[i].y - m);
    v[i].z = __expf(v[i].z - m); v[i].w = __expf(v[i].w - m);
    s += (v[i].x + v[i].y) + (v[i].z + v[i].w);
  }
  #pragma unroll
  for (int o = 32; o; o >>= 1) s += __shfl_xor(s, o);
  if (lane == 0) red[4 + wave] = s;
  __syncthreads();
  s = (red[4] + red[5]) + (red[6] + red[7]);

  float inv = 1.0f / s;
  #pragma unroll
  for (int i = 0; i < 4; ++i) {
    v[i].x *= inv; v[i].y *= inv; v[i].z *= inv; v[i].w *= inv;
    ((float4*)p)[i * 256 + tid] = v[i];
  }
  if (tid < HDIM) zbuf[bh * HDIM + tid] = 0.f;
}

// ---------------------------------------------------------------------------
// outp[bh][d] += sum_n w[bh][n] * X[b][n][h*64+d].  grid (8 chunks, 64 bh).
// ---------------------------------------------------------------------------
__global__ __launch_bounds__(256) void accum_weighted(
    const u16* __restrict__ X, const float* __restrict__ w,
    float* __restrict__ outp)
{
  const int bh = blockIdx.y, chunk = blockIdx.x;
  const int b = bh >> 4, h = bh & 15;
  const int tid = threadIdx.x, lane = tid & 63, wave = tid >> 6;
  const int rsub = lane >> 3, cl = lane & 7;
  const size_t base = (size_t)b * SEQ * DIM + h * HDIM;
  const int n0 = chunk * 512;

  float acc[8] = {0, 0, 0, 0, 0, 0, 0, 0};
  for (int it = 0; it < 16; ++it) {
    int n = n0 + it * 32 + wave * 8 + rsub;
    u16x8 u = *(const u16x8*)(X + base + (size_t)n * DIM + cl * 8);
    float wv = w[(size_t)bh * SEQ + n];
    #pragma unroll
    for (int j = 0; j < 8; ++j) acc[j] += wv * bf2f(u[j]);
  }
  #pragma unroll
  for (int j = 0; j < 8; ++j) {
    acc[j] += __shfl_xor(acc[j], 8);
    acc[j] += __shfl_xor(acc[j], 16);
    acc[j] += __shfl_xor(acc[j], 32);
  }
  __shared__ float part[4][64];
  if (rsub == 0) {
    #pragma unroll
    for (int j = 0; j < 8; ++j) part[wave][cl * 8 + j] = acc[j];
  }
  __syncthreads();
  if (tid < HDIM) {
    float s = (part[0][tid] + part[1][tid]) + (part[2][tid] + part[3][tid]);
    atomicAdd(&outp[bh * HDIM + tid], s);
  }
}

// ---------------------------------------------------------------------------
// vecb[bh][d] = gq[bh][d] * k_beta[h][d] * SCALE.  16 blocks.
// ---------------------------------------------------------------------------
__global__ __launch_bounds__(256) void make_vecb(
    const float* __restrict__ gq, const float* __restrict__ kbeta,
    float* __restrict__ vecb)
{
  int t = blockIdx.x * 256 + threadIdx.x;
  int h = (t >> 6) & 15, d = t & 63;
  vecb[t] = gq[t] * kbeta[h * HDIM + d] * SCALEF;
}

// ---------------------------------------------------------------------------
// Beta logits: lb[b*16+h][n] = dot(K[b][n][h*64:+64], vecb[b*16+h]).
// ---------------------------------------------------------------------------
__global__ __launch_bounds__(256) void logits_beta(
    const u16* __restrict__ Kb, const float* __restrict__ vecb,
    float* __restrict__ lb)
{
  __shared__ float vb[NHEAD][HDIM];
  const int rg = blockIdx.x;
  const int b = rg >> 8;
  const int tid = threadIdx.x, lane = tid & 63, wave = tid >> 6;

  for (int i = tid; i < NHEAD * HDIM; i += 256)
    ((float*)vb)[i] = vecb[b * DIM + i];
  __syncthreads();

  const int h = lane >> 2, dq = (lane & 3) * 16;
  #pragma unroll
  for (int i = 0; i < 4; ++i) {
    int gr = rg * 16 + wave * 4 + i;
    const u16* rp = Kb + (size_t)gr * DIM + h * HDIM + dq;
    u16x8 u0 = *(const u16x8*)rp;
    u16x8 u1 = *(const u16x8*)(rp + 8);
    float dot = 0.f;
    #pragma unroll
    for (int j = 0; j < 8; ++j) dot += bf2f(u0[j]) * vb[h][dq + j];
    #pragma unroll
    for (int j = 0; j < 8; ++j) dot += bf2f(u1[j]) * vb[h][dq + 8 + j];
    dot += __shfl_xor(dot, 1);
    dot += __shfl_xor(dot, 2);
    if ((lane & 3) == 0) {
      lb[((size_t)b * NHEAD + h) * SEQ + (gr & (SEQ - 1))] = dot;
    }
  }
}

// ---------------------------------------------------------------------------
// c2[b,j] = sum_k gv[b,k]*Wo[j,k] + bo[j].  One wave per (b,j); 1024 blocks.
// ---------------------------------------------------------------------------
__global__ __launch_bounds__(256) void gv_wo_kernel(
    const float* __restrict__ gv, const float* __restrict__ Wo,
    const float* __restrict__ bo, float* __restrict__ c2)
{
  int wid = blockIdx.x * 4 + (threadIdx.x >> 6);
  int b = wid >> 10, j = wid & 1023;
  int lane = threadIdx.x & 63;
  float acc = 0.f;
  #pragma unroll
  for (int c = 0; c < 16; ++c) {
    int kk = c * 64 + lane;
    acc += gv[b * DIM + kk] * Wo[(size_t)j * DIM + kk];
  }
  #pragma unroll
  for (int o = 32; o; o >>= 1) acc += __shfl_down(acc, o);
  if (lane == 0) c2[wid] = acc + bo[j];
}

// ---------------------------------------------------------------------------
extern "C" void kernel_launch(void* const* d_in, const int* in_sizes, int n_in,
                              void* d_out, int out_size, void* d_ws, size_t ws_size,
                              hipStream_t stream) {
  const float* q  = (const float*)d_in[0];
  const float* k  = (const float*)d_in[1];
  const float* v  = (const float*)d_in[2];
  const float* Wq = (const float*)d_in[3];
  const float* bq = (const float*)d_in[4];
  const float* Wk = (const float*)d_in[5];
  const float* bk = (const float*)d_in[6];
  const float* Wv = (const float*)d_in[7];
  const float* bv = (const float*)d_in[8];
  const float* qa = (const float*)d_in[9];
  const float* kb = (const float*)d_in[10];
  const float* Wo = (const float*)d_in[11];
  const float* bo = (const float*)d_in[12];
  float* out = (float*)d_out;

  // workspace layout (~111 MB)
  u16* Qb  = (u16*)d_ws;
  u16* Kb  = Qb + (size_t)MROWS * DIM;
  u16* Vb  = Kb + (size_t)MROWS * DIM;
  u16* Wqb = Vb + (size_t)MROWS * DIM;
  u16* Wkb = Wqb + (size_t)DIM * DIM;
  u16* Wvb = Wkb + (size_t)DIM * DIM;
  u16* Wob = Wvb + (size_t)DIM * DIM;
  float* la   = (float*)(Wob + (size_t)DIM * DIM);
  float* lb   = la + (size_t)NB * NHEAD * SEQ;
  float* gq   = lb + (size_t)NB * NHEAD * SEQ;
  float* gv   = gq + NB * DIM;
  float* vecb = gv + NB * DIM;
  float* c2   = vecb + NB * DIM;

  // bf16 activation staging buffer lives in d_out (dead until final GEMM)
  u16* actb = (u16*)d_out;

  const dim3 g256(MROWS / 256, DIM / 256);   // (64, 4)
  const size_t ldsb = 131072;

  cvt_weights<<<2048, 256, 0, stream>>>(Wq, Wk, Wv, Wo, Wqb, Wkb, Wvb, Wob);

  cvt_act<<<8192, 256, 0, stream>>>(q, actb);
  gemm256<0><<<g256, 512, ldsb, stream>>>(actb, Wqb, bq, Qb, nullptr, nullptr, 1, qa, la);
  cvt_act<<<8192, 256, 0, stream>>>(k, actb);
  gemm256<0><<<g256, 512, ldsb, stream>>>(actb, Wkb, bk, Kb, nullptr, nullptr, 0, qa, la);
  cvt_act<<<8192, 256, 0, stream>>>(v, actb);
  gemm256<0><<<g256, 512, ldsb, stream>>>(actb, Wvb, bv, Vb, nullptr, nullptr, 0, qa, la);

  softmax_norm<<<64, 256, 0, stream>>>(la, gq);
  accum_weighted<<<dim3(8, 64), 256, 0, stream>>>(Qb, la, gq);
  make_vecb<<<16, 256, 0, stream>>>(gq, kb, vecb);
  logits_beta<<<1024, 256, 0, stream>>>(Kb, vecb, lb);
  softmax_norm<<<64, 256, 0, stream>>>(lb, gv);
  accum_weighted<<<dim3(8, 64), 256, 0, stream>>>(Vb, lb, gv);
  gv_wo_kernel<<<1024, 256, 0, stream>>>(gv, Wo, bo, c2);
  gemm256<1><<<g256, 512, ldsb, stream>>>(Qb, Wob, nullptr, nullptr, out, c2, 0, qa, la);
}

// Round 6
// 250.386 us; speedup vs baseline: 2.2642x; 1.2313x over previous
//
#include <hip/hip_runtime.h>
#include <hip/hip_bf16.h>
#include <cstdint>
#include <cstddef>

// Problem constants
#define SEQ    4096
#define NB     4
#define DIM    1024
#define NHEAD  16
#define HDIM   64
#define MROWS  (NB * SEQ)   // 16384
#define SCALEF 0.125f       // 64^-0.5
#define NT     16           // K tiles of 64

typedef short          s16x8 __attribute__((ext_vector_type(8)));
typedef unsigned short u16x8 __attribute__((ext_vector_type(8)));
typedef float          f32x4 __attribute__((ext_vector_type(4)));
typedef unsigned short u16;

__device__ __forceinline__ u16 f2bf(float f) {
  return __builtin_bit_cast(u16, __float2bfloat16(f));
}
__device__ __forceinline__ float bf2f(u16 u) {
  return __builtin_bit_cast(float, (uint32_t)u << 16);
}
__device__ __forceinline__ void gload_lds16(const void* g, void* l) {
  __builtin_amdgcn_global_load_lds(
      (const __attribute__((address_space(1))) void*)g,
      (__attribute__((address_space(3))) void*)l, 16, 0, 0);
}

// ---------------------------------------------------------------------------
// Convert the four [DIM,DIM] fp32 weight matrices to bf16.
// ---------------------------------------------------------------------------
__global__ __launch_bounds__(256) void cvt_weights(
    const float* __restrict__ w0, const float* __restrict__ w1,
    const float* __restrict__ w2, const float* __restrict__ w3,
    u16* __restrict__ o0, u16* __restrict__ o1,
    u16* __restrict__ o2, u16* __restrict__ o3)
{
  int t = blockIdx.x * 256 + threadIdx.x;
  int m = t >> 17;
  int off = (t & 131071) * 8;
  const float* s = (m == 0) ? w0 : (m == 1) ? w1 : (m == 2) ? w2 : w3;
  u16*         d = (m == 0) ? o0 : (m == 1) ? o1 : (m == 2) ? o2 : o3;
  float4 a = ((const float4*)(s + off))[0];
  float4 b = ((const float4*)(s + off))[1];
  u16x8 p;
  p[0] = f2bf(a.x); p[1] = f2bf(a.y); p[2] = f2bf(a.z); p[3] = f2bf(a.w);
  p[4] = f2bf(b.x); p[5] = f2bf(b.y); p[6] = f2bf(b.z); p[7] = f2bf(b.w);
  *(u16x8*)(d + off) = p;
}

// ---------------------------------------------------------------------------
// Convert one [MROWS,DIM] fp32 activation matrix to bf16. 8192 blocks.
// ---------------------------------------------------------------------------
__global__ __launch_bounds__(256) void cvt_act(
    const float* __restrict__ s, u16* __restrict__ d)
{
  int t = blockIdx.x * 256 + threadIdx.x;
  int off = t * 8;
  float4 a = ((const float4*)(s + off))[0];
  float4 b = ((const float4*)(s + off))[1];
  u16x8 p;
  p[0] = f2bf(a.x); p[1] = f2bf(a.y); p[2] = f2bf(a.z); p[3] = f2bf(a.w);
  p[4] = f2bf(b.x); p[5] = f2bf(b.y); p[6] = f2bf(b.z); p[7] = f2bf(b.w);
  *(u16x8*)(d + off) = p;
}

// ---------------------------------------------------------------------------
// 256x256-tile phase-split GEMM (T2+T3+T4+T5), BK=64, 8 waves (2Mx4N), 512thr.
// LDS (dynamic 128KB): A[2][256][64] bf16 @0, B[2][256][64] bf16 @65536.
// T2 swizzle (rule #21, both-sides): LDS dest linear (gload_lds), global
// SOURCE column pre-swizzled by ((t&7)^((t>>3)&7)), ds_read byte addr applies
// the same involution byte ^= ((row&7)<<4). Kills the 16-way ds_read_b128
// conflict (lanes fr=0..7 -> 8 distinct 16B slots covering all 32 banks).
// Schedule: 4 quadrant phases/K-tile, one half-tile staged per phase into the
// idle parity set (exception Ah0(t+2) -> current set, fenced by phase-2's
// read-drain barrier); raw s_barrier; per-tile checkpoint vmcnt(2).
// MODE 0: C = A@W^T + bias -> bf16 (+optional fused alpha logits).
// MODE 1: C = A@W^T + c2[batch] -> fp32.
// ---------------------------------------------------------------------------
template<int MODE>
__global__ __launch_bounds__(512) void gemm256(
    const u16* __restrict__ A, const u16* __restrict__ W,
    const float* __restrict__ bias, u16* __restrict__ Cb, float* __restrict__ Cf,
    const float* __restrict__ c2, int do_alpha,
    const float* __restrict__ qalpha, float* __restrict__ la)
{
  extern __shared__ __align__(16) char smem[];
  const int tid = threadIdx.x;
  const int lane = tid & 63, wave = tid >> 6;
  const int wr = wave >> 2, wc = wave & 3;          // 2 (M) x 4 (N)
  const int fr = lane & 15, fq = lane >> 4;
  const int m0 = blockIdx.x * 256, n0 = blockIdx.y * 256;
  const int wrow = wr * 128, wcol = wc * 64;

  const int arow = tid >> 3;                         // staging row 0..63
  const int scol = (((tid & 7) ^ ((tid >> 3) & 7)) * 8);  // pre-swizzled src col

  f32x4 acc[8][4];
  #pragma unroll
  for (int i = 0; i < 8; ++i)
    #pragma unroll
    for (int j = 0; j < 4; ++j) acc[i][j] = (f32x4){0.f, 0.f, 0.f, 0.f};

  auto stA = [&](int kt, int h) {
    const u16* g = A + (size_t)(m0 + h * 128) * DIM + kt * 64;
    char* l = smem + (kt & 1) * 32768 + h * 16384;
    gload_lds16(g + (size_t)arow * DIM + scol,        l + tid * 16);
    gload_lds16(g + (size_t)(64 + arow) * DIM + scol, l + 8192 + tid * 16);
  };
  auto stB = [&](int kt, int h) {
    const u16* g = W + (size_t)(n0 + h * 128) * DIM + kt * 64;
    char* l = smem + 65536 + (kt & 1) * 32768 + h * 16384;
    gload_lds16(g + (size_t)arow * DIM + scol,        l + tid * 16);
    gload_lds16(g + (size_t)(64 + arow) * DIM + scol, l + 8192 + tid * 16);
  };
  // swizzled LDS byte offset for row R (0..255), k-slice ks, quad fq
  auto ldsoff = [&](int R, int ks) -> size_t {
    return (size_t)R * 128 + (size_t)((ks * 64 + fq * 16) ^ ((R & 7) << 4));
  };

  // ---- prologue: tile0 fully + Ah0(1); tile0 landed via vmcnt(2) ----
  stA(0, 0); stA(0, 1); stB(0, 0); stB(0, 1);
  stA(1, 0);
  asm volatile("s_waitcnt vmcnt(2)" ::: "memory");
  asm volatile("s_barrier" ::: "memory");

  for (int t = 0; t < NT; ++t) {
    const char* Abase = smem + (t & 1) * 32768;
    const char* Bbase = smem + 65536 + (t & 1) * 32768;
    s16x8 areg[4][2];
    #pragma unroll
    for (int p = 0; p < 4; ++p) {
      const int mq = p >> 1, nq = p & 1;
      // ds-reads for this quadrant (swizzled addresses)
      s16x8 breg[2][2];
      #pragma unroll
      for (int j = 0; j < 2; ++j)
        #pragma unroll
        for (int ks = 0; ks < 2; ++ks)
          breg[j][ks] = *(const s16x8*)(Bbase + ldsoff(wcol + (nq * 2 + j) * 16 + fr, ks));
      if (nq == 0) {
        #pragma unroll
        for (int i = 0; i < 4; ++i)
          #pragma unroll
          for (int ks = 0; ks < 2; ++ks)
            areg[i][ks] = *(const s16x8*)(Abase + ldsoff(wrow + (mq * 4 + i) * 16 + fr, ks));
      }
      // stage one half-tile
      if (p == 0 && t + 1 < NT) stA(t + 1, 1);
      if (p == 1 && t + 1 < NT) stB(t + 1, 0);
      if (p == 2 && t + 1 < NT) stB(t + 1, 1);
      if (p == 3 && t + 2 < NT) stA(t + 2, 0);

      asm volatile("s_barrier" ::: "memory");
      __builtin_amdgcn_s_setprio(1);
      #pragma unroll
      for (int i = 0; i < 4; ++i)
        #pragma unroll
        for (int j = 0; j < 2; ++j)
          #pragma unroll
          for (int ks = 0; ks < 2; ++ks)
            acc[mq * 4 + i][nq * 2 + j] = __builtin_amdgcn_mfma_f32_16x16x32_bf16(
                areg[i][ks], breg[j][ks], acc[mq * 4 + i][nq * 2 + j], 0, 0, 0);
      __builtin_amdgcn_s_setprio(0);
      if (p < 3) {
        asm volatile("s_barrier" ::: "memory");
      } else {
        if (t == NT - 2) asm volatile("s_waitcnt vmcnt(0)" ::: "memory");
        else             asm volatile("s_waitcnt vmcnt(2)" ::: "memory");
        asm volatile("s_barrier" ::: "memory");
      }
    }
  }

  // ---- epilogue ----
  if constexpr (MODE == 0) {
    #pragma unroll
    for (int ni = 0; ni < 4; ++ni) {
      const int col = n0 + wcol + ni * 16 + fr;
      const float bvv = bias[col];
      #pragma unroll
      for (int mi = 0; mi < 8; ++mi)
        #pragma unroll
        for (int r = 0; r < 4; ++r)
          acc[mi][ni][r] += bvv;
    }
    #pragma unroll
    for (int ni = 0; ni < 4; ++ni) {
      const int col = n0 + wcol + ni * 16 + fr;
      #pragma unroll
      for (int mi = 0; mi < 8; ++mi) {
        #pragma unroll
        for (int r = 0; r < 4; ++r) {
          const int row = m0 + wrow + mi * 16 + fq * 4 + r;
          Cb[(size_t)row * DIM + col] = f2bf(acc[mi][ni][r]);
        }
      }
    }
    if (do_alpha) {
      const int h = (n0 >> 6) + wc;
      float qa0 = qalpha[h * HDIM + 0 * 16 + fr];
      float qa1 = qalpha[h * HDIM + 1 * 16 + fr];
      float qa2 = qalpha[h * HDIM + 2 * 16 + fr];
      float qa3 = qalpha[h * HDIM + 3 * 16 + fr];
      #pragma unroll
      for (int mi = 0; mi < 8; ++mi) {
        #pragma unroll
        for (int r = 0; r < 4; ++r) {
          float p = acc[mi][0][r] * qa0 + acc[mi][1][r] * qa1
                  + acc[mi][2][r] * qa2 + acc[mi][3][r] * qa3;
          p += __shfl_xor(p, 1);
          p += __shfl_xor(p, 2);
          p += __shfl_xor(p, 4);
          p += __shfl_xor(p, 8);
          if (fr == 0) {
            const int row = m0 + wrow + mi * 16 + fq * 4 + r;
            la[((size_t)(row >> 12) * NHEAD + h) * SEQ + (row & (SEQ - 1))] = p * SCALEF;
          }
        }
      }
    }
  } else {
    const int bidx = m0 >> 12;
    #pragma unroll
    for (int ni = 0; ni < 4; ++ni) {
      const int col = n0 + wcol + ni * 16 + fr;
      const float cv = c2[bidx * DIM + col];
      #pragma unroll
      for (int mi = 0; mi < 8; ++mi) {
        #pragma unroll
        for (int r = 0; r < 4; ++r) {
          const int row = m0 + wrow + mi * 16 + fq * 4 + r;
          Cf[(size_t)row * DIM + col] = acc[mi][ni][r] + cv;
        }
      }
    }
  }
}

// ---------------------------------------------------------------------------
// Softmax normalize l[bh][0..SEQ) in place; zero zbuf[bh][64]. 64 blocks.
// ---------------------------------------------------------------------------
__global__ __launch_bounds__(256) void softmax_norm(
    float* __restrict__ l, float* __restrict__ zbuf)
{
  const int bh = blockIdx.x;
  const int tid = threadIdx.x, lane = tid & 63, wave = tid >> 6;
  float* p = l + (size_t)bh * SEQ;
  __shared__ float red[8];

  float4 v[4];
  #pragma unroll
  for (int i = 0; i < 4; ++i) v[i] = ((const float4*)p)[i * 256 + tid];

  float m = -1e30f;
  #pragma unroll
  for (int i = 0; i < 4; ++i)
    m = fmaxf(m, fmaxf(fmaxf(v[i].x, v[i].y), fmaxf(v[i].z, v[i].w)));
  #pragma unroll
  for (int o = 32; o; o >>= 1) m = fmaxf(m, __shfl_xor(m, o));
  if (lane == 0) red[wave] = m;
  __syncthreads();
  m = fmaxf(fmaxf(red[0], red[1]), fmaxf(red[2], red[3]));

  float s = 0.f;
  #pragma unroll
  for (int i = 0; i < 4; ++i) {
    v[i].x = __expf(v[i].x - m); v[i].y = __expf(v[i].y - m);
    v[i].z = __expf(v[i].z - m); v[i].w = __expf(v[i].w - m);
    s += (v[i].x + v[i].y) + (v[i].z + v[i].w);
  }
  #pragma unroll
  for (int o = 32; o; o >>= 1) s += __shfl_xor(s, o);
  if (lane == 0) red[4 + wave] = s;
  __syncthreads();
  s = (red[4] + red[5]) + (red[6] + red[7]);

  float inv = 1.0f / s;
  #pragma unroll
  for (int i = 0; i < 4; ++i) {
    v[i].x *= inv; v[i].y *= inv; v[i].z *= inv; v[i].w *= inv;
    ((float4*)p)[i * 256 + tid] = v[i];
  }
  if (tid < HDIM) zbuf[bh * HDIM + tid] = 0.f;
}

// ---------------------------------------------------------------------------
// outp[bh][d] += sum_n w[bh][n] * X[b][n][h*64+d].  grid (8 chunks, 64 bh).
// ---------------------------------------------------------------------------
__global__ __launch_bounds__(256) void accum_weighted(
    const u16* __restrict__ X, const float* __restrict__ w,
    float* __restrict__ outp)
{
  const int bh = blockIdx.y, chunk = blockIdx.x;
  const int b = bh >> 4, h = bh & 15;
  const int tid = threadIdx.x, lane = tid & 63, wave = tid >> 6;
  const int rsub = lane >> 3, cl = lane & 7;
  const size_t base = (size_t)b * SEQ * DIM + h * HDIM;
  const int n0 = chunk * 512;

  float acc[8] = {0, 0, 0, 0, 0, 0, 0, 0};
  for (int it = 0; it < 16; ++it) {
    int n = n0 + it * 32 + wave * 8 + rsub;
    u16x8 u = *(const u16x8*)(X + base + (size_t)n * DIM + cl * 8);
    float wv = w[(size_t)bh * SEQ + n];
    #pragma unroll
    for (int j = 0; j < 8; ++j) acc[j] += wv * bf2f(u[j]);
  }
  #pragma unroll
  for (int j = 0; j < 8; ++j) {
    acc[j] += __shfl_xor(acc[j], 8);
    acc[j] += __shfl_xor(acc[j], 16);
    acc[j] += __shfl_xor(acc[j], 32);
  }
  __shared__ float part[4][64];
  if (rsub == 0) {
    #pragma unroll
    for (int j = 0; j < 8; ++j) part[wave][cl * 8 + j] = acc[j];
  }
  __syncthreads();
  if (tid < HDIM) {
    float s = (part[0][tid] + part[1][tid]) + (part[2][tid] + part[3][tid]);
    atomicAdd(&outp[bh * HDIM + tid], s);
  }
}

// ---------------------------------------------------------------------------
// vecb[bh][d] = gq[bh][d] * k_beta[h][d] * SCALE.  16 blocks.
// ---------------------------------------------------------------------------
__global__ __launch_bounds__(256) void make_vecb(
    const float* __restrict__ gq, const float* __restrict__ kbeta,
    float* __restrict__ vecb)
{
  int t = blockIdx.x * 256 + threadIdx.x;
  int h = (t >> 6) & 15, d = t & 63;
  vecb[t] = gq[t] * kbeta[h * HDIM + d] * SCALEF;
}

// ---------------------------------------------------------------------------
// Beta logits: lb[b*16+h][n] = dot(K[b][n][h*64:+64], vecb[b*16+h]).
// ---------------------------------------------------------------------------
__global__ __launch_bounds__(256) void logits_beta(
    const u16* __restrict__ Kb, const float* __restrict__ vecb,
    float* __restrict__ lb)
{
  __shared__ float vb[NHEAD][HDIM];
  const int rg = blockIdx.x;
  const int b = rg >> 8;
  const int tid = threadIdx.x, lane = tid & 63, wave = tid >> 6;

  for (int i = tid; i < NHEAD * HDIM; i += 256)
    ((float*)vb)[i] = vecb[b * DIM + i];
  __syncthreads();

  const int h = lane >> 2, dq = (lane & 3) * 16;
  #pragma unroll
  for (int i = 0; i < 4; ++i) {
    int gr = rg * 16 + wave * 4 + i;
    const u16* rp = Kb + (size_t)gr * DIM + h * HDIM + dq;
    u16x8 u0 = *(const u16x8*)rp;
    u16x8 u1 = *(const u16x8*)(rp + 8);
    float dot = 0.f;
    #pragma unroll
    for (int j = 0; j < 8; ++j) dot += bf2f(u0[j]) * vb[h][dq + j];
    #pragma unroll
    for (int j = 0; j < 8; ++j) dot += bf2f(u1[j]) * vb[h][dq + 8 + j];
    dot += __shfl_xor(dot, 1);
    dot += __shfl_xor(dot, 2);
    if ((lane & 3) == 0) {
      lb[((size_t)b * NHEAD + h) * SEQ + (gr & (SEQ - 1))] = dot;
    }
  }
}

// ---------------------------------------------------------------------------
// c2[b,j] = sum_k gv[b,k]*Wo[j,k] + bo[j].  One wave per (b,j); 1024 blocks.
// ---------------------------------------------------------------------------
__global__ __launch_bounds__(256) void gv_wo_kernel(
    const float* __restrict__ gv, const float* __restrict__ Wo,
    const float* __restrict__ bo, float* __restrict__ c2)
{
  int wid = blockIdx.x * 4 + (threadIdx.x >> 6);
  int b = wid >> 10, j = wid & 1023;
  int lane = threadIdx.x & 63;
  float acc = 0.f;
  #pragma unroll
  for (int c = 0; c < 16; ++c) {
    int kk = c * 64 + lane;
    acc += gv[b * DIM + kk] * Wo[(size_t)j * DIM + kk];
  }
  #pragma unroll
  for (int o = 32; o; o >>= 1) acc += __shfl_down(acc, o);
  if (lane == 0) c2[wid] = acc + bo[j];
}

// ---------------------------------------------------------------------------
extern "C" void kernel_launch(void* const* d_in, const int* in_sizes, int n_in,
                              void* d_out, int out_size, void* d_ws, size_t ws_size,
                              hipStream_t stream) {
  const float* q  = (const float*)d_in[0];
  const float* k  = (const float*)d_in[1];
  const float* v  = (const float*)d_in[2];
  const float* Wq = (const float*)d_in[3];
  const float* bq = (const float*)d_in[4];
  const float* Wk = (const float*)d_in[5];
  const float* bk = (const float*)d_in[6];
  const float* Wv = (const float*)d_in[7];
  const float* bv = (const float*)d_in[8];
  const float* qa = (const float*)d_in[9];
  const float* kb = (const float*)d_in[10];
  const float* Wo = (const float*)d_in[11];
  const float* bo = (const float*)d_in[12];
  float* out = (float*)d_out;

  // workspace layout (~111 MB)
  u16* Qb  = (u16*)d_ws;
  u16* Kb  = Qb + (size_t)MROWS * DIM;
  u16* Vb  = Kb + (size_t)MROWS * DIM;
  u16* Wqb = Vb + (size_t)MROWS * DIM;
  u16* Wkb = Wqb + (size_t)DIM * DIM;
  u16* Wvb = Wkb + (size_t)DIM * DIM;
  u16* Wob = Wvb + (size_t)DIM * DIM;
  float* la   = (float*)(Wob + (size_t)DIM * DIM);
  float* lb   = la + (size_t)NB * NHEAD * SEQ;
  float* gq   = lb + (size_t)NB * NHEAD * SEQ;
  float* gv   = gq + NB * DIM;
  float* vecb = gv + NB * DIM;
  float* c2   = vecb + NB * DIM;

  // bf16 activation staging buffer lives in d_out (dead until final GEMM)
  u16* actb = (u16*)d_out;

  const dim3 g256(MROWS / 256, DIM / 256);   // (64, 4)
  const size_t ldsb = 131072;

  cvt_weights<<<2048, 256, 0, stream>>>(Wq, Wk, Wv, Wo, Wqb, Wkb, Wvb, Wob);

  cvt_act<<<8192, 256, 0, stream>>>(q, actb);
  gemm256<0><<<g256, 512, ldsb, stream>>>(actb, Wqb, bq, Qb, nullptr, nullptr, 1, qa, la);
  cvt_act<<<8192, 256, 0, stream>>>(k, actb);
  gemm256<0><<<g256, 512, ldsb, stream>>>(actb, Wkb, bk, Kb, nullptr, nullptr, 0, qa, la);
  cvt_act<<<8192, 256, 0, stream>>>(v, actb);
  gemm256<0><<<g256, 512, ldsb, stream>>>(actb, Wvb, bv, Vb, nullptr, nullptr, 0, qa, la);

  softmax_norm<<<64, 256, 0, stream>>>(la, gq);
  accum_weighted<<<dim3(8, 64), 256, 0, stream>>>(Qb, la, gq);
  make_vecb<<<16, 256, 0, stream>>>(gq, kb, vecb);
  logits_beta<<<1024, 256, 0, stream>>>(Kb, vecb, lb);
  softmax_norm<<<64, 256, 0, stream>>>(lb, gv);
  accum_weighted<<<dim3(8, 64), 256, 0, stream>>>(Vb, lb, gv);
  gv_wo_kernel<<<1024, 256, 0, stream>>>(gv, Wo, bo, c2);
  gemm256<1><<<g256, 512, ldsb, stream>>>(Qb, Wob, nullptr, nullptr, out, c2, 0, qa, la);
}